// Round 4
// baseline (396.417 us; speedup 1.0000x reference)
//
#include <hip/hip_runtime.h>
#include <stdint.h>

#define BB 4
#define CC 256
#define NN 4096   // H*W = 64*64
#define RR 32
#define NCHUNK 8
#define JSTEPS (NN / NCHUNK / 32)   // 16
#define CSIZE  (NN / NCHUNK)        // 512

typedef __attribute__((ext_vector_type(8)))  short  short8;   // 8 bf16 (MFMA A/B frag)
typedef __attribute__((ext_vector_type(4)))  short  short4v;  // 4 bf16 = 8B
typedef __attribute__((ext_vector_type(16))) float  floatx16; // MFMA C/D frag

static __device__ __forceinline__ unsigned short f2bf(float f) {
    union { float f; unsigned int u; } v; v.f = f;
    unsigned int u = v.u;
    u += 0x7fffu + ((u >> 16) & 1u);
    return (unsigned short)(u >> 16);
}

static __device__ __forceinline__ float bf2f(unsigned short u) {
    union { unsigned int u; float f; } v; v.u = ((unsigned int)u) << 16;
    return v.f;
}

static __device__ __forceinline__ float exp2_fast(float x) {
#if __has_builtin(__builtin_amdgcn_exp2f)
    return __builtin_amdgcn_exp2f(x);
#else
    return exp2f(x);
#endif
}

// ---------------- K1: depthwise 3x3, all 3 dilations -> D bf16 --------------
// grid (C, B), block 256 = 4 waves; wave = 16-h strip, lane = w. 26 x-rows in
// registers (x read exactly once); horizontal taps via shfl (CSE'd per phase).
// D layout: [p][b][c][n] bf16.
__global__ __launch_bounds__(256, 4) void k_dw(
    const float* __restrict__ x,
    const float* __restrict__ w1, const float* __restrict__ b1,
    const float* __restrict__ w2, const float* __restrict__ b2,
    const float* __restrict__ w3, const float* __restrict__ b3,
    unsigned short* __restrict__ Dq)
{
    int t = threadIdx.x, lane = t & 63, wv = t >> 6;
    int c = blockIdx.x, b = blockIdx.y;
    int hb = wv * 16;
    const float* xc = x + ((size_t)(b * CC + c)) * NN;
    float row[26];
    #pragma unroll
    for (int k = 0; k < 26; k++) {
        int rr = hb - 5 + k;
        int rc = rr < 0 ? 0 : (rr > 63 ? 63 : rr);
        float v = xc[rc * 64 + lane];
        row[k] = (rr >= 0 && rr <= 63) ? v : 0.f;
    }
    const float* DWW[3] = {w1, w2, w3};
    const float* DWB[3] = {b1, b2, b3};
    #pragma unroll
    for (int p = 0; p < 3; p++) {
        const int d = (p == 0) ? 1 : (p == 1 ? 3 : 5);
        float wt[9];
        #pragma unroll
        for (int q = 0; q < 9; q++) wt[q] = DWW[p][c * 9 + q];
        float bias = DWB[p][c];
        bool okl = lane >= d, okr = lane < 64 - d;
        int lml = okl ? lane - d : 0;
        int lpr = okr ? lane + d : 63;
        float sm[26], sp[26];
        #pragma unroll
        for (int k = 5 - d; k <= 20 + d; k++) {
            float a = __shfl(row[k], lml, 64); sm[k] = okl ? a : 0.f;
            float q2 = __shfl(row[k], lpr, 64); sp[k] = okr ? q2 : 0.f;
        }
        unsigned short* Dp = Dq + (((size_t)p * BB + b) * CC + c) * NN;
        #pragma unroll
        for (int hl = 0; hl < 16; hl++) {
            int k0 = hl + 5 - d, k1 = hl + 5, k2 = hl + 5 + d;
            float o = bias
                + wt[0] * sm[k0] + wt[1] * row[k0] + wt[2] * sp[k0]
                + wt[3] * sm[k1] + wt[4] * row[k1] + wt[5] * sp[k1]
                + wt[6] * sm[k2] + wt[7] * row[k2] + wt[8] * sp[k2];
            Dp[(hb + hl) * 64 + lane] = f2bf(o);
        }
    }
}

// ---------------- K2: pointwise C->R from D, c-split + LDS reduce -----------
// grid (64 ntiles, 3 p, B), block 512 = 8 waves; wave wv reduces c in
// [32wv,32wv+32). Reduce + output code identical to the verified R3 path.
__global__ __launch_bounds__(512, 4) void k_pw(
    const unsigned short* __restrict__ Dq,
    const float* __restrict__ p1, const float* __restrict__ pb1,
    const float* __restrict__ p2, const float* __restrict__ pb2,
    const float* __restrict__ p3, const float* __restrict__ pb3,
    unsigned short* __restrict__ V, unsigned short* __restrict__ Qt,
    unsigned short* __restrict__ Kt)
{
    __shared__ float part[8][32][64];   // 64 KB
    int t = threadIdx.x, lane = t & 63, wv = t >> 6;
    int nt = blockIdx.x, p = blockIdx.y, b = blockIdx.z;
    int n = nt * 64 + lane;
    const float* pw  = (p == 0) ? p1  : (p == 1 ? p2  : p3);
    const float* pwb = (p == 0) ? pb1 : (p == 1 ? pb2 : pb3);
    const unsigned short* Dp = Dq + (((size_t)p * BB + b) * CC) * NN + n;
    float acc[32];
    #pragma unroll
    for (int r = 0; r < 32; r++) acc[r] = 0.f;
    #pragma unroll 4
    for (int ci = 0; ci < 32; ci++) {
        int c = wv * 32 + ci;
        float dv = bf2f(Dp[(size_t)c * NN]);
        #pragma unroll
        for (int r = 0; r < 32; r++) acc[r] += dv * pw[r * CC + c];  // uniform -> s_load
    }
    #pragma unroll
    for (int r = 0; r < 32; r++) part[wv][r][lane] = acc[r];
    __syncthreads();
    int rg = wv;
    if (p == 0) {
        #pragma unroll
        for (int j = 0; j < 4; j++) {
            int r = rg * 4 + j;
            float s = pwb[r];
            #pragma unroll
            for (int w2 = 0; w2 < 8; w2++) s += part[w2][r][lane];
            V[((size_t)(b * RR + r)) * NN + n] = f2bf(s);            // V[b][r][n]
        }
    } else {
        const float sc = (p == 1) ? 1.4426950408889634f : 1.f;       // Q *= log2e
        unsigned short* outp = (p == 1) ? Qt : Kt;
        short4v vv;
        #pragma unroll
        for (int j = 0; j < 4; j++) {
            int r = rg * 4 + j;
            float s = pwb[r];
            #pragma unroll
            for (int w2 = 0; w2 < 8; w2++) s += part[w2][r][lane];
            vv[j] = (short)f2bf(s * sc);
        }
        *(short4v*)(outp + ((size_t)b * NN + n) * RR + rg * 4) = vv; // [b][n][r]
    }
}

// ---------------- K3: fused attention, LDS-staged V, 8 chunks ----------------
__global__ __launch_bounds__(256, 4) void k_attn(
    const unsigned short* __restrict__ Qt, const unsigned short* __restrict__ Kt,
    const unsigned short* __restrict__ V, float* __restrict__ OP, float* __restrict__ LP)
{
    __shared__ unsigned short Vt[32][36];   // padded rows: conflict-free frags
    int t = threadIdx.x;
    int wave = t >> 6, lane = t & 63, l31 = lane & 31, h = lane >> 5;
    int itile = blockIdx.x * 4 + wave;
    int chunk = blockIdx.y;
    int b = blockIdx.z;
    int i = itile * 32 + l31;

    const short8* qrow = (const short8*)(Qt + ((size_t)b * NN + i) * RR);
    short8 q1 = qrow[h], q2 = qrow[2 + h];

    const unsigned short* Kb = Kt + (size_t)b * NN * RR;
    const unsigned short* Vb = V + (size_t)b * RR * NN;

    int sr = t >> 3, sc = t & 7;
    const unsigned short* vsrc = Vb + (size_t)sr * NN + chunk * CSIZE + sc * 4;

    floatx16 acc = {};
    float lacc = 0.f;

    short4v vreg = *(const short4v*)vsrc;
    const short8* krow0 = (const short8*)(Kb + (size_t)(chunk * CSIZE + l31) * RR);
    short8 ka1 = krow0[h], ka2 = krow0[2 + h];

    for (int js = 0; js < JSTEPS; js++) {
        __syncthreads();
        *(short4v*)(&Vt[sr][sc * 4]) = vreg;
        int jn = (js + 1 < JSTEPS) ? js + 1 : js;
        vreg = *(const short4v*)(vsrc + jn * 32);
        __syncthreads();

        floatx16 st = {};
        st = __builtin_amdgcn_mfma_f32_32x32x16_bf16(ka1, q1, st, 0, 0, 0);
        st = __builtin_amdgcn_mfma_f32_32x32x16_bf16(ka2, q2, st, 0, 0, 0);
        const short8* krow = (const short8*)(Kb + (size_t)(chunk * CSIZE + jn * 32 + l31) * RR);
        ka1 = krow[h]; ka2 = krow[2 + h];

        float p[16];
        #pragma unroll
        for (int r = 0; r < 16; r++) { p[r] = exp2_fast(st[r]); lacc += p[r]; }
        short8 pa1, pa2;
        #pragma unroll
        for (int r = 0; r < 8; r++) {
            pa1[r] = (short)f2bf(p[r]);
            pa2[r] = (short)f2bf(p[r + 8]);
        }
        const unsigned short* vrow = &Vt[l31][0];
        short4v v0 = *(const short4v*)(vrow + 4 * h);
        short4v v1 = *(const short4v*)(vrow + 8 + 4 * h);
        short4v v2 = *(const short4v*)(vrow + 16 + 4 * h);
        short4v v3 = *(const short4v*)(vrow + 24 + 4 * h);
        short8 vb1, vb2;
        #pragma unroll
        for (int q = 0; q < 4; q++) {
            vb1[q] = v0[q]; vb1[q + 4] = v1[q];
            vb2[q] = v2[q]; vb2[q + 4] = v3[q];
        }
        acc = __builtin_amdgcn_mfma_f32_32x32x16_bf16(pa1, vb1, acc, 0, 0, 0);
        acc = __builtin_amdgcn_mfma_f32_32x32x16_bf16(pa2, vb2, acc, 0, 0, 0);
    }
    size_t slot = ((size_t)(b * 128 + itile) * NCHUNK + chunk) * 64 + lane;
    float* op = OP + slot * 16;
    #pragma unroll
    for (int r = 0; r < 16; r++) op[r] = acc[r];
    LP[slot] = lacc;
}

// ---------------- K4: merge chunk partials -> FMt[b][n][r] bf16 -------------
__global__ void k_merge(const float* __restrict__ OP, const float* __restrict__ LP,
                        unsigned short* __restrict__ FMt) {
    int itile = blockIdx.x, b = blockIdx.y;
    int lane = threadIdx.x, l31 = lane & 31, h = lane >> 5;
    __shared__ float linv[32];
    size_t base = (size_t)(b * 128 + itile) * NCHUNK;
    float ls = 0.f;
    #pragma unroll
    for (int ch = 0; ch < NCHUNK; ch++) ls += LP[(base + ch) * 64 + lane];
    ls += __shfl_xor(ls, 32, 64);                  // combine the two j-halves
    if (lane < 32) linv[lane] = 1.f / ls;          // index = i_local = l31
    __syncthreads();
    float o[16];
    #pragma unroll
    for (int r = 0; r < 16; r++) o[r] = 0.f;
    for (int ch = 0; ch < NCHUNK; ch++) {
        const float* op = OP + ((base + ch) * 64 + lane) * 16;
        #pragma unroll
        for (int r = 0; r < 16; r++) o[r] += op[r];
    }
    int ibase = itile * 32;
    #pragma unroll
    for (int r = 0; r < 16; r++) {
        int il = (r & 3) + 8 * (r >> 2) + 4 * h;   // C/D row mapping
        FMt[((size_t)b * NN + (ibase + il)) * RR + l31] = f2bf(o[r] * linv[il]);
    }
}

// ---------------- K5: 1x1 conv R->C via MFMA + bias + residual --------------
// grid (32 ngroups, 8 cotiles, B), block 256 = 4 waves (4 n-subtiles of 32).
__global__ __launch_bounds__(256, 4) void k_convout(
    const float* __restrict__ x, const unsigned short* __restrict__ FMt,
    const float* __restrict__ cw, const float* __restrict__ cb,
    float* __restrict__ out)
{
    int t = threadIdx.x, lane = t & 63, l31 = lane & 31, h = lane >> 5, wv = t >> 6;
    int ng = blockIdx.x, ct = blockIdx.y, b = blockIdx.z;
    int n0 = ng * 128 + wv * 32;
    int co0 = ct * 32;
    // A frags (cw fp32 [co][32] -> bf16): lane m=l31 -> co, k = 8h+j (+16)
    const float* cwp = cw + (size_t)(co0 + l31) * RR + 8 * h;
    short8 a1, a2;
    #pragma unroll
    for (int j = 0; j < 8; j++) {
        a1[j] = (short)f2bf(cwp[j]);
        a2[j] = (short)f2bf(cwp[16 + j]);
    }
    // B frags (FMt bf16 [b][n][r]): lane n=l31+n0, k = 8h+j (+16)
    const unsigned short* fp = FMt + ((size_t)b * NN + n0 + l31) * RR + 8 * h;
    short8 b1 = *(const short8*)fp;
    short8 b2 = *(const short8*)(fp + 16);
    floatx16 acc = {};
    acc = __builtin_amdgcn_mfma_f32_32x32x16_bf16(a1, b1, acc, 0, 0, 0);
    acc = __builtin_amdgcn_mfma_f32_32x32x16_bf16(a2, b2, acc, 0, 0, 0);
    #pragma unroll
    for (int rr = 0; rr < 16; rr++) {
        int co = co0 + (rr & 3) + 8 * (rr >> 2) + 4 * h;
        size_t o = ((size_t)(b * CC + co)) * NN + n0 + l31;
        out[o] = x[o] + acc[rr] + cb[co];
    }
}

extern "C" void kernel_launch(void* const* d_in, const int* in_sizes, int n_in,
                              void* d_out, int out_size, void* d_ws, size_t ws_size,
                              hipStream_t stream) {
    const float* x = (const float*)d_in[0];
    char* ws = (char*)d_ws;
    // D (24 MB, dead after k_pw) aliases OP (16 MB, written by k_attn)
    unsigned short* Dq = (unsigned short*)(ws);               // 24 MB [p][b][c][n]
    float*          OP = (float*)(ws);                        // 16 MB (alias of D)
    unsigned short* Qt = (unsigned short*)(ws + 25165824);    // 1 MB (b,n,r)
    unsigned short* Kt = (unsigned short*)(ws + 26214400);    // 1 MB (b,n,r)
    unsigned short* V  = (unsigned short*)(ws + 27262976);    // 1 MB (b,r,n)
    float*          LP = (float*)(ws + 28311552);             // 1 MB
    unsigned short* FMt= (unsigned short*)(ws + 29360128);    // 1 MB (b,n,r)

    hipLaunchKernelGGL(k_dw, dim3(CC, BB), dim3(256), 0, stream, x,
                       (const float*)d_in[1], (const float*)d_in[2],
                       (const float*)d_in[5], (const float*)d_in[6],
                       (const float*)d_in[9], (const float*)d_in[10], Dq);
    hipLaunchKernelGGL(k_pw, dim3(64, 3, BB), dim3(512), 0, stream, Dq,
                       (const float*)d_in[3], (const float*)d_in[4],
                       (const float*)d_in[7], (const float*)d_in[8],
                       (const float*)d_in[11], (const float*)d_in[12],
                       V, Qt, Kt);
    hipLaunchKernelGGL(k_attn, dim3(32, NCHUNK, BB), dim3(256), 0, stream, Qt, Kt, V, OP, LP);
    hipLaunchKernelGGL(k_merge, dim3(128, BB), dim3(64), 0, stream, OP, LP, FMt);
    hipLaunchKernelGGL(k_convout, dim3(32, 8, BB), dim3(256), 0, stream,
                       x, FMt, (const float*)d_in[13], (const float*)d_in[14], (float*)d_out);
}

// Round 5
// 189.525 us; speedup vs baseline: 2.0916x; 2.0916x over previous
//
#include <hip/hip_runtime.h>
#include <stdint.h>

#define BB 4
#define CC 256
#define NN 4096   // H*W = 64*64
#define RR 32
#define NCHUNK 8
#define JSTEPS (NN / NCHUNK / 32)   // 16
#define CSIZE  (NN / NCHUNK)        // 512

typedef __attribute__((ext_vector_type(8)))  short  short8;   // 8 bf16 (MFMA A/B frag)
typedef __attribute__((ext_vector_type(4)))  short  short4v;  // 4 bf16 = 8B
typedef __attribute__((ext_vector_type(16))) float  floatx16; // MFMA C/D frag

static __device__ __forceinline__ unsigned short f2bf(float f) {
    union { float f; unsigned int u; } v; v.f = f;
    unsigned int u = v.u;
    u += 0x7fffu + ((u >> 16) & 1u);
    return (unsigned short)(u >> 16);
}

static __device__ __forceinline__ float bf2f(unsigned short u) {
    union { unsigned int u; float f; } v; v.u = ((unsigned int)u) << 16;
    return v.f;
}

static __device__ __forceinline__ float exp2_fast(float x) {
#if __has_builtin(__builtin_amdgcn_exp2f)
    return __builtin_amdgcn_exp2f(x);
#else
    return exp2f(x);
#endif
}

// ---------------- K1: depthwise 3x3, all 3 dilations -> D bf16 --------------
// grid (C, B), block 256 = 4 waves; wave = 16-h strip, lane = w. 26 x-rows in
// registers (x read exactly once); horizontal taps via shfl (CSE'd per phase).
// D layout: [p][b][c][n] bf16.
__global__ __launch_bounds__(256, 4) void k_dw(
    const float* __restrict__ x,
    const float* __restrict__ w1, const float* __restrict__ b1,
    const float* __restrict__ w2, const float* __restrict__ b2,
    const float* __restrict__ w3, const float* __restrict__ b3,
    unsigned short* __restrict__ Dq)
{
    int t = threadIdx.x, lane = t & 63, wv = t >> 6;
    int c = blockIdx.x, b = blockIdx.y;
    int hb = wv * 16;
    const float* xc = x + ((size_t)(b * CC + c)) * NN;
    float row[26];
    #pragma unroll
    for (int k = 0; k < 26; k++) {
        int rr = hb - 5 + k;
        int rc = rr < 0 ? 0 : (rr > 63 ? 63 : rr);
        float v = xc[rc * 64 + lane];
        row[k] = (rr >= 0 && rr <= 63) ? v : 0.f;
    }
    const float* DWW[3] = {w1, w2, w3};
    const float* DWB[3] = {b1, b2, b3};
    #pragma unroll
    for (int p = 0; p < 3; p++) {
        const int d = (p == 0) ? 1 : (p == 1 ? 3 : 5);
        float wt[9];
        #pragma unroll
        for (int q = 0; q < 9; q++) wt[q] = DWW[p][c * 9 + q];
        float bias = DWB[p][c];
        bool okl = lane >= d, okr = lane < 64 - d;
        int lml = okl ? lane - d : 0;
        int lpr = okr ? lane + d : 63;
        float sm[26], sp[26];
        #pragma unroll
        for (int k = 5 - d; k <= 20 + d; k++) {
            float a = __shfl(row[k], lml, 64); sm[k] = okl ? a : 0.f;
            float q2 = __shfl(row[k], lpr, 64); sp[k] = okr ? q2 : 0.f;
        }
        unsigned short* Dp = Dq + (((size_t)p * BB + b) * CC + c) * NN;
        #pragma unroll
        for (int hl = 0; hl < 16; hl++) {
            int k0 = hl + 5 - d, k1 = hl + 5, k2 = hl + 5 + d;
            float o = bias
                + wt[0] * sm[k0] + wt[1] * row[k0] + wt[2] * sp[k0]
                + wt[3] * sm[k1] + wt[4] * row[k1] + wt[5] * sp[k1]
                + wt[6] * sm[k2] + wt[7] * row[k2] + wt[8] * sp[k2];
            Dp[(hb + hl) * 64 + lane] = f2bf(o);
        }
    }
}

// ---------------- K2: pointwise C->R from D (round-1-proven shape) ----------
// grid (64 ntiles, 3 p, B), block 256 = 64 n x 4 r-groups, acc[8]/thread.
__global__ __launch_bounds__(256, 4) void k_pw(
    const unsigned short* __restrict__ Dq,
    const float* __restrict__ p1, const float* __restrict__ pb1,
    const float* __restrict__ p2, const float* __restrict__ pb2,
    const float* __restrict__ p3, const float* __restrict__ pb3,
    unsigned short* __restrict__ V, unsigned short* __restrict__ Qt,
    unsigned short* __restrict__ Kt)
{
    int t = threadIdx.x;
    int nt = blockIdx.x, p = blockIdx.y, b = blockIdx.z;
    int n  = nt * 64 + (t & 63);
    int rg = t >> 6;                     // 0..3 -> r = rg*8..rg*8+7
    const float* pw  = (p == 0) ? p1  : (p == 1 ? p2  : p3);
    const float* pwb = (p == 0) ? pb1 : (p == 1 ? pb2 : pb3);
    float acc[8];
    #pragma unroll
    for (int j = 0; j < 8; j++) acc[j] = pwb[rg * 8 + j];
    const unsigned short* Dp = Dq + (((size_t)p * BB + b) * CC) * NN + n;
    #pragma unroll 4
    for (int c = 0; c < CC; c++) {
        float dv = bf2f(Dp[(size_t)c * NN]);
        #pragma unroll
        for (int j = 0; j < 8; j++) acc[j] += dv * pw[(rg * 8 + j) * CC + c];
    }
    if (p == 0) {
        #pragma unroll
        for (int j = 0; j < 8; j++)
            V[((size_t)(b * RR + rg * 8 + j)) * NN + n] = f2bf(acc[j]);  // V[b][r][n]
    } else {
        const float sc = (p == 1) ? 1.4426950408889634f : 1.f;           // Q *= log2e
        unsigned short* outp = (p == 1) ? Qt : Kt;
        short8 vv;
        #pragma unroll
        for (int j = 0; j < 8; j++) vv[j] = (short)f2bf(acc[j] * sc);
        *(short8*)(outp + ((size_t)b * NN + n) * RR + rg * 8) = vv;      // [b][n][r]
    }
}

// ---------------- K3: fused attention, LDS-staged V, 8 chunks ----------------
__global__ __launch_bounds__(256, 4) void k_attn(
    const unsigned short* __restrict__ Qt, const unsigned short* __restrict__ Kt,
    const unsigned short* __restrict__ V, float* __restrict__ OP, float* __restrict__ LP)
{
    __shared__ unsigned short Vt[32][36];   // padded rows: conflict-free frags
    int t = threadIdx.x;
    int wave = t >> 6, lane = t & 63, l31 = lane & 31, h = lane >> 5;
    int itile = blockIdx.x * 4 + wave;
    int chunk = blockIdx.y;
    int b = blockIdx.z;
    int i = itile * 32 + l31;

    const short8* qrow = (const short8*)(Qt + ((size_t)b * NN + i) * RR);
    short8 q1 = qrow[h], q2 = qrow[2 + h];

    const unsigned short* Kb = Kt + (size_t)b * NN * RR;
    const unsigned short* Vb = V + (size_t)b * RR * NN;

    int sr = t >> 3, sc = t & 7;
    const unsigned short* vsrc = Vb + (size_t)sr * NN + chunk * CSIZE + sc * 4;

    floatx16 acc = {};
    float lacc = 0.f;

    short4v vreg = *(const short4v*)vsrc;
    const short8* krow0 = (const short8*)(Kb + (size_t)(chunk * CSIZE + l31) * RR);
    short8 ka1 = krow0[h], ka2 = krow0[2 + h];

    for (int js = 0; js < JSTEPS; js++) {
        __syncthreads();
        *(short4v*)(&Vt[sr][sc * 4]) = vreg;
        int jn = (js + 1 < JSTEPS) ? js + 1 : js;
        vreg = *(const short4v*)(vsrc + jn * 32);
        __syncthreads();

        floatx16 st = {};
        st = __builtin_amdgcn_mfma_f32_32x32x16_bf16(ka1, q1, st, 0, 0, 0);
        st = __builtin_amdgcn_mfma_f32_32x32x16_bf16(ka2, q2, st, 0, 0, 0);
        const short8* krow = (const short8*)(Kb + (size_t)(chunk * CSIZE + jn * 32 + l31) * RR);
        ka1 = krow[h]; ka2 = krow[2 + h];

        float p[16];
        #pragma unroll
        for (int r = 0; r < 16; r++) { p[r] = exp2_fast(st[r]); lacc += p[r]; }
        short8 pa1, pa2;
        #pragma unroll
        for (int r = 0; r < 8; r++) {
            pa1[r] = (short)f2bf(p[r]);
            pa2[r] = (short)f2bf(p[r + 8]);
        }
        const unsigned short* vrow = &Vt[l31][0];
        short4v v0 = *(const short4v*)(vrow + 4 * h);
        short4v v1 = *(const short4v*)(vrow + 8 + 4 * h);
        short4v v2 = *(const short4v*)(vrow + 16 + 4 * h);
        short4v v3 = *(const short4v*)(vrow + 24 + 4 * h);
        short8 vb1, vb2;
        #pragma unroll
        for (int q = 0; q < 4; q++) {
            vb1[q] = v0[q]; vb1[q + 4] = v1[q];
            vb2[q] = v2[q]; vb2[q + 4] = v3[q];
        }
        acc = __builtin_amdgcn_mfma_f32_32x32x16_bf16(pa1, vb1, acc, 0, 0, 0);
        acc = __builtin_amdgcn_mfma_f32_32x32x16_bf16(pa2, vb2, acc, 0, 0, 0);
    }
    size_t slot = ((size_t)(b * 128 + itile) * NCHUNK + chunk) * 64 + lane;
    float* op = OP + slot * 16;
    #pragma unroll
    for (int r = 0; r < 16; r++) op[r] = acc[r];
    LP[slot] = lacc;
}

// ---------------- K4: merge chunk partials -> FMt[b][n][r] bf16 -------------
__global__ void k_merge(const float* __restrict__ OP, const float* __restrict__ LP,
                        unsigned short* __restrict__ FMt) {
    int itile = blockIdx.x, b = blockIdx.y;
    int lane = threadIdx.x, l31 = lane & 31, h = lane >> 5;
    __shared__ float linv[32];
    size_t base = (size_t)(b * 128 + itile) * NCHUNK;
    float ls = 0.f;
    #pragma unroll
    for (int ch = 0; ch < NCHUNK; ch++) ls += LP[(base + ch) * 64 + lane];
    ls += __shfl_xor(ls, 32, 64);                  // combine the two j-halves
    if (lane < 32) linv[lane] = 1.f / ls;          // index = i_local = l31
    __syncthreads();
    float o[16];
    #pragma unroll
    for (int r = 0; r < 16; r++) o[r] = 0.f;
    for (int ch = 0; ch < NCHUNK; ch++) {
        const float* op = OP + ((base + ch) * 64 + lane) * 16;
        #pragma unroll
        for (int r = 0; r < 16; r++) o[r] += op[r];
    }
    int ibase = itile * 32;
    #pragma unroll
    for (int r = 0; r < 16; r++) {
        int il = (r & 3) + 8 * (r >> 2) + 4 * h;   // C/D row mapping
        FMt[((size_t)b * NN + (ibase + il)) * RR + l31] = f2bf(o[r] * linv[il]);
    }
}

// ---------------- K5: 1x1 conv R->C via MFMA + bias + residual --------------
// grid (32 ngroups, 8 cotiles, B), block 256 = 4 waves (4 n-subtiles of 32).
__global__ __launch_bounds__(256, 4) void k_convout(
    const float* __restrict__ x, const unsigned short* __restrict__ FMt,
    const float* __restrict__ cw, const float* __restrict__ cb,
    float* __restrict__ out)
{
    int t = threadIdx.x, lane = t & 63, l31 = lane & 31, h = lane >> 5, wv = t >> 6;
    int ng = blockIdx.x, ct = blockIdx.y, b = blockIdx.z;
    int n0 = ng * 128 + wv * 32;
    int co0 = ct * 32;
    // A frags (cw fp32 [co][32] -> bf16): lane m=l31 -> co, k = 8h+j (+16)
    const float* cwp = cw + (size_t)(co0 + l31) * RR + 8 * h;
    short8 a1, a2;
    #pragma unroll
    for (int j = 0; j < 8; j++) {
        a1[j] = (short)f2bf(cwp[j]);
        a2[j] = (short)f2bf(cwp[16 + j]);
    }
    // B frags (FMt bf16 [b][n][r]): lane n=l31+n0, k = 8h+j (+16)
    const unsigned short* fp = FMt + ((size_t)b * NN + n0 + l31) * RR + 8 * h;
    short8 b1 = *(const short8*)fp;
    short8 b2 = *(const short8*)(fp + 16);
    floatx16 acc = {};
    acc = __builtin_amdgcn_mfma_f32_32x32x16_bf16(a1, b1, acc, 0, 0, 0);
    acc = __builtin_amdgcn_mfma_f32_32x32x16_bf16(a2, b2, acc, 0, 0, 0);
    #pragma unroll
    for (int rr = 0; rr < 16; rr++) {
        int co = co0 + (rr & 3) + 8 * (rr >> 2) + 4 * h;
        size_t o = ((size_t)(b * CC + co)) * NN + n0 + l31;
        out[o] = x[o] + acc[rr] + cb[co];
    }
}

extern "C" void kernel_launch(void* const* d_in, const int* in_sizes, int n_in,
                              void* d_out, int out_size, void* d_ws, size_t ws_size,
                              hipStream_t stream) {
    const float* x = (const float*)d_in[0];
    char* ws = (char*)d_ws;
    // D (24 MB, dead after k_pw) aliases OP (16 MB, written by k_attn)
    unsigned short* Dq = (unsigned short*)(ws);               // 24 MB [p][b][c][n]
    float*          OP = (float*)(ws);                        // 16 MB (alias of D)
    unsigned short* Qt = (unsigned short*)(ws + 25165824);    // 1 MB (b,n,r)
    unsigned short* Kt = (unsigned short*)(ws + 26214400);    // 1 MB (b,n,r)
    unsigned short* V  = (unsigned short*)(ws + 27262976);    // 1 MB (b,r,n)
    float*          LP = (float*)(ws + 28311552);             // 1 MB
    unsigned short* FMt= (unsigned short*)(ws + 29360128);    // 1 MB (b,n,r)

    hipLaunchKernelGGL(k_dw, dim3(CC, BB), dim3(256), 0, stream, x,
                       (const float*)d_in[1], (const float*)d_in[2],
                       (const float*)d_in[5], (const float*)d_in[6],
                       (const float*)d_in[9], (const float*)d_in[10], Dq);
    hipLaunchKernelGGL(k_pw, dim3(64, 3, BB), dim3(256), 0, stream, Dq,
                       (const float*)d_in[3], (const float*)d_in[4],
                       (const float*)d_in[7], (const float*)d_in[8],
                       (const float*)d_in[11], (const float*)d_in[12],
                       V, Qt, Kt);
    hipLaunchKernelGGL(k_attn, dim3(32, NCHUNK, BB), dim3(256), 0, stream, Qt, Kt, V, OP, LP);
    hipLaunchKernelGGL(k_merge, dim3(128, BB), dim3(64), 0, stream, OP, LP, FMt);
    hipLaunchKernelGGL(k_convout, dim3(32, 8, BB), dim3(256), 0, stream,
                       x, FMt, (const float*)d_in[13], (const float*)d_in[14], (float*)d_out);
}

// Round 6
// 144.846 us; speedup vs baseline: 2.7368x; 1.3085x over previous
//
#include <hip/hip_runtime.h>
#include <stdint.h>

#define BB 4
#define CC 256
#define NN 4096   // H*W = 64*64
#define RR 32
#define NCHUNK 8
#define JSTEPS (NN / NCHUNK / 32)   // 16
#define CSIZE  (NN / NCHUNK)        // 512

typedef __attribute__((ext_vector_type(8)))  short  short8;   // 8 bf16 (MFMA A/B frag)
typedef __attribute__((ext_vector_type(4)))  short  short4v;  // 4 bf16 = 8B
typedef __attribute__((ext_vector_type(16))) float  floatx16; // MFMA C/D frag

static __device__ __forceinline__ unsigned short f2bf(float f) {
    union { float f; unsigned int u; } v; v.f = f;
    unsigned int u = v.u;
    u += 0x7fffu + ((u >> 16) & 1u);
    return (unsigned short)(u >> 16);
}

static __device__ __forceinline__ float bf2f(unsigned short u) {
    union { unsigned int u; float f; } v; v.u = ((unsigned int)u) << 16;
    return v.f;
}

static __device__ __forceinline__ float exp2_fast(float x) {
#if __has_builtin(__builtin_amdgcn_exp2f)
    return __builtin_amdgcn_exp2f(x);
#else
    return exp2f(x);
#endif
}

// ---------------- K1: depthwise 3x3, all 3 dilations -> D bf16 --------------
// grid (C, B), block 256 = 4 waves; wave = 16-h strip, lane = w. 26 x-rows in
// registers (x read exactly once); horizontal taps via shfl (CSE'd per phase).
// D layout: [p][b][c][n] bf16.
__global__ __launch_bounds__(256, 4) void k_dw(
    const float* __restrict__ x,
    const float* __restrict__ w1, const float* __restrict__ b1,
    const float* __restrict__ w2, const float* __restrict__ b2,
    const float* __restrict__ w3, const float* __restrict__ b3,
    unsigned short* __restrict__ Dq)
{
    int t = threadIdx.x, lane = t & 63, wv = t >> 6;
    int c = blockIdx.x, b = blockIdx.y;
    int hb = wv * 16;
    const float* xc = x + ((size_t)(b * CC + c)) * NN;
    float row[26];
    #pragma unroll
    for (int k = 0; k < 26; k++) {
        int rr = hb - 5 + k;
        int rc = rr < 0 ? 0 : (rr > 63 ? 63 : rr);
        float v = xc[rc * 64 + lane];
        row[k] = (rr >= 0 && rr <= 63) ? v : 0.f;
    }
    const float* DWW[3] = {w1, w2, w3};
    const float* DWB[3] = {b1, b2, b3};
    #pragma unroll
    for (int p = 0; p < 3; p++) {
        const int d = (p == 0) ? 1 : (p == 1 ? 3 : 5);
        float wt[9];
        #pragma unroll
        for (int q = 0; q < 9; q++) wt[q] = DWW[p][c * 9 + q];
        float bias = DWB[p][c];
        bool okl = lane >= d, okr = lane < 64 - d;
        int lml = okl ? lane - d : 0;
        int lpr = okr ? lane + d : 63;
        float sm[26], sp[26];
        #pragma unroll
        for (int k = 5 - d; k <= 20 + d; k++) {
            float a = __shfl(row[k], lml, 64); sm[k] = okl ? a : 0.f;
            float q2 = __shfl(row[k], lpr, 64); sp[k] = okr ? q2 : 0.f;
        }
        unsigned short* Dp = Dq + (((size_t)p * BB + b) * CC + c) * NN;
        #pragma unroll
        for (int hl = 0; hl < 16; hl++) {
            int k0 = hl + 5 - d, k1 = hl + 5, k2 = hl + 5 + d;
            float o = bias
                + wt[0] * sm[k0] + wt[1] * row[k0] + wt[2] * sp[k0]
                + wt[3] * sm[k1] + wt[4] * row[k1] + wt[5] * sp[k1]
                + wt[6] * sm[k2] + wt[7] * row[k2] + wt[8] * sp[k2];
            Dp[(hb + hl) * 64 + lane] = f2bf(o);
        }
    }
}

// ---------------- K2: pointwise C->R as MFMA GEMM ---------------------------
// grid (32 ntiles of 128 n, 3 p, B), block 256 = 4 waves; wave = 32r x 32n,
// K=256 = 16 x mfma_32x32x16. A = pw bf16 (LDS-staged), B = D[c][n] gathers.
__global__ __launch_bounds__(256, 4) void k_pw(
    const unsigned short* __restrict__ Dq,
    const float* __restrict__ p1, const float* __restrict__ pb1,
    const float* __restrict__ p2, const float* __restrict__ pb2,
    const float* __restrict__ p3, const float* __restrict__ pb3,
    unsigned short* __restrict__ V, unsigned short* __restrict__ Qt,
    unsigned short* __restrict__ Kt)
{
    __shared__ unsigned short PW[32 * 264];        // pw bf16, row stride 264 (16B-aligned)
    __shared__ unsigned short Lt[4][32][40];       // per-wave [n][r] transpose buffer
    int t = threadIdx.x, lane = t & 63, l31 = lane & 31, h = lane >> 5, wv = t >> 6;
    int ntile = blockIdx.x, p = blockIdx.y, b = blockIdx.z;
    const float* pw  = (p == 0) ? p1  : (p == 1 ? p2  : p3);
    const float* pwb = (p == 0) ? pb1 : (p == 1 ? pb2 : pb3);

    // stage pw -> bf16 LDS: thread r = t>>3, 32-col block (t&7)*32
    {
        int r = t >> 3, cb0 = (t & 7) * 32;
        const float4* src = (const float4*)(pw + r * CC + cb0);
        #pragma unroll
        for (int g = 0; g < 8; g++) {
            float4 f = src[g];
            short4v s4;
            s4[0] = (short)f2bf(f.x); s4[1] = (short)f2bf(f.y);
            s4[2] = (short)f2bf(f.z); s4[3] = (short)f2bf(f.w);
            *(short4v*)&PW[r * 264 + cb0 + g * 4] = s4;
        }
    }
    __syncthreads();

    int n = ntile * 128 + wv * 32 + l31;
    // B base: c = 8h folded in; element j of frag kt -> c = kt*16 + 8h + j
    const unsigned short* Dn = Dq + (((size_t)p * BB + b) * CC + 8 * h) * NN + n;
    floatx16 acc = {};
    #pragma unroll 4
    for (int kt = 0; kt < 16; kt++) {
        short8 af = *(const short8*)&PW[l31 * 264 + kt * 16 + 8 * h];
        short8 bf;
        #pragma unroll
        for (int j = 0; j < 8; j++) bf[j] = (short)Dn[(size_t)(kt * 16 + j) * NN];
        acc = __builtin_amdgcn_mfma_f32_32x32x16_bf16(af, bf, acc, 0, 0, 0);
    }

    if (p == 0) {
        #pragma unroll
        for (int rr = 0; rr < 16; rr++) {
            int r = (rr & 3) + 8 * (rr >> 2) + 4 * h;          // C/D row mapping
            V[((size_t)(b * RR + r)) * NN + n] = f2bf(acc[rr] + pwb[r]);  // V[b][r][n]
        }
    } else {
        const float sc = (p == 1) ? 1.4426950408889634f : 1.f; // Q *= log2e
        unsigned short* outp = (p == 1) ? Qt : Kt;
        #pragma unroll
        for (int rr = 0; rr < 16; rr++) {
            int r = (rr & 3) + 8 * (rr >> 2) + 4 * h;
            Lt[wv][l31][r] = f2bf((acc[rr] + pwb[r]) * sc);
        }
        __threadfence_block();   // order wave-local LDS write->read (lockstep lanes)
        unsigned short* orow = outp + ((size_t)b * NN + n) * RR + h * 16;
        short8 lo = *(const short8*)&Lt[wv][l31][h * 16];
        *(short8*)orow = lo;                                   // [b][n][r], 32B/lane
        short8 hi = *(const short8*)&Lt[wv][l31][h * 16 + 8];
        *(short8*)(orow + 8) = hi;
    }
}

// ---------------- K3: fused attention, LDS-staged V, 8 chunks ----------------
__global__ __launch_bounds__(256, 4) void k_attn(
    const unsigned short* __restrict__ Qt, const unsigned short* __restrict__ Kt,
    const unsigned short* __restrict__ V, float* __restrict__ OP, float* __restrict__ LP)
{
    __shared__ unsigned short Vt[32][36];   // padded rows: conflict-free frags
    int t = threadIdx.x;
    int wave = t >> 6, lane = t & 63, l31 = lane & 31, h = lane >> 5;
    int itile = blockIdx.x * 4 + wave;
    int chunk = blockIdx.y;
    int b = blockIdx.z;
    int i = itile * 32 + l31;

    const short8* qrow = (const short8*)(Qt + ((size_t)b * NN + i) * RR);
    short8 q1 = qrow[h], q2 = qrow[2 + h];

    const unsigned short* Kb = Kt + (size_t)b * NN * RR;
    const unsigned short* Vb = V + (size_t)b * RR * NN;

    int sr = t >> 3, sc = t & 7;
    const unsigned short* vsrc = Vb + (size_t)sr * NN + chunk * CSIZE + sc * 4;

    floatx16 acc = {};
    float lacc = 0.f;

    short4v vreg = *(const short4v*)vsrc;
    const short8* krow0 = (const short8*)(Kb + (size_t)(chunk * CSIZE + l31) * RR);
    short8 ka1 = krow0[h], ka2 = krow0[2 + h];

    for (int js = 0; js < JSTEPS; js++) {
        __syncthreads();
        *(short4v*)(&Vt[sr][sc * 4]) = vreg;
        int jn = (js + 1 < JSTEPS) ? js + 1 : js;
        vreg = *(const short4v*)(vsrc + jn * 32);
        __syncthreads();

        floatx16 st = {};
        st = __builtin_amdgcn_mfma_f32_32x32x16_bf16(ka1, q1, st, 0, 0, 0);
        st = __builtin_amdgcn_mfma_f32_32x32x16_bf16(ka2, q2, st, 0, 0, 0);
        const short8* krow = (const short8*)(Kb + (size_t)(chunk * CSIZE + jn * 32 + l31) * RR);
        ka1 = krow[h]; ka2 = krow[2 + h];

        float p[16];
        #pragma unroll
        for (int r = 0; r < 16; r++) { p[r] = exp2_fast(st[r]); lacc += p[r]; }
        short8 pa1, pa2;
        #pragma unroll
        for (int r = 0; r < 8; r++) {
            pa1[r] = (short)f2bf(p[r]);
            pa2[r] = (short)f2bf(p[r + 8]);
        }
        const unsigned short* vrow = &Vt[l31][0];
        short4v v0 = *(const short4v*)(vrow + 4 * h);
        short4v v1 = *(const short4v*)(vrow + 8 + 4 * h);
        short4v v2 = *(const short4v*)(vrow + 16 + 4 * h);
        short4v v3 = *(const short4v*)(vrow + 24 + 4 * h);
        short8 vb1, vb2;
        #pragma unroll
        for (int q = 0; q < 4; q++) {
            vb1[q] = v0[q]; vb1[q + 4] = v1[q];
            vb2[q] = v2[q]; vb2[q + 4] = v3[q];
        }
        acc = __builtin_amdgcn_mfma_f32_32x32x16_bf16(pa1, vb1, acc, 0, 0, 0);
        acc = __builtin_amdgcn_mfma_f32_32x32x16_bf16(pa2, vb2, acc, 0, 0, 0);
    }
    size_t slot = ((size_t)(b * 128 + itile) * NCHUNK + chunk) * 64 + lane;
    float* op = OP + slot * 16;
    #pragma unroll
    for (int r = 0; r < 16; r++) op[r] = acc[r];
    LP[slot] = lacc;
}

// ---------------- K4: merge chunk partials -> FMt[b][n][r] bf16 -------------
__global__ void k_merge(const float* __restrict__ OP, const float* __restrict__ LP,
                        unsigned short* __restrict__ FMt) {
    int itile = blockIdx.x, b = blockIdx.y;
    int lane = threadIdx.x, l31 = lane & 31, h = lane >> 5;
    __shared__ float linv[32];
    size_t base = (size_t)(b * 128 + itile) * NCHUNK;
    float ls = 0.f;
    #pragma unroll
    for (int ch = 0; ch < NCHUNK; ch++) ls += LP[(base + ch) * 64 + lane];
    ls += __shfl_xor(ls, 32, 64);                  // combine the two j-halves
    if (lane < 32) linv[lane] = 1.f / ls;          // index = i_local = l31
    __syncthreads();
    float o[16];
    #pragma unroll
    for (int r = 0; r < 16; r++) o[r] = 0.f;
    for (int ch = 0; ch < NCHUNK; ch++) {
        const float* op = OP + ((base + ch) * 64 + lane) * 16;
        #pragma unroll
        for (int r = 0; r < 16; r++) o[r] += op[r];
    }
    int ibase = itile * 32;
    #pragma unroll
    for (int r = 0; r < 16; r++) {
        int il = (r & 3) + 8 * (r >> 2) + 4 * h;   // C/D row mapping
        FMt[((size_t)b * NN + (ibase + il)) * RR + l31] = f2bf(o[r] * linv[il]);
    }
}

// ---------------- K5: 1x1 conv R->C via MFMA + bias + residual --------------
// grid (32 ngroups, 8 cotiles, B), block 256 = 4 waves (4 n-subtiles of 32).
__global__ __launch_bounds__(256, 4) void k_convout(
    const float* __restrict__ x, const unsigned short* __restrict__ FMt,
    const float* __restrict__ cw, const float* __restrict__ cb,
    float* __restrict__ out)
{
    int t = threadIdx.x, lane = t & 63, l31 = lane & 31, h = lane >> 5, wv = t >> 6;
    int ng = blockIdx.x, ct = blockIdx.y, b = blockIdx.z;
    int n0 = ng * 128 + wv * 32;
    int co0 = ct * 32;
    // A frags (cw fp32 [co][32] -> bf16): lane m=l31 -> co, k = 8h+j (+16)
    const float* cwp = cw + (size_t)(co0 + l31) * RR + 8 * h;
    short8 a1, a2;
    #pragma unroll
    for (int j = 0; j < 8; j++) {
        a1[j] = (short)f2bf(cwp[j]);
        a2[j] = (short)f2bf(cwp[16 + j]);
    }
    // B frags (FMt bf16 [b][n][r]): lane n=l31+n0, k = 8h+j (+16)
    const unsigned short* fp = FMt + ((size_t)b * NN + n0 + l31) * RR + 8 * h;
    short8 b1 = *(const short8*)fp;
    short8 b2 = *(const short8*)(fp + 16);
    floatx16 acc = {};
    acc = __builtin_amdgcn_mfma_f32_32x32x16_bf16(a1, b1, acc, 0, 0, 0);
    acc = __builtin_amdgcn_mfma_f32_32x32x16_bf16(a2, b2, acc, 0, 0, 0);
    #pragma unroll
    for (int rr = 0; rr < 16; rr++) {
        int co = co0 + (rr & 3) + 8 * (rr >> 2) + 4 * h;
        size_t o = ((size_t)(b * CC + co)) * NN + n0 + l31;
        out[o] = x[o] + acc[rr] + cb[co];
    }
}

extern "C" void kernel_launch(void* const* d_in, const int* in_sizes, int n_in,
                              void* d_out, int out_size, void* d_ws, size_t ws_size,
                              hipStream_t stream) {
    const float* x = (const float*)d_in[0];
    char* ws = (char*)d_ws;
    // D (24 MB, dead after k_pw) aliases OP (16 MB, written by k_attn)
    unsigned short* Dq = (unsigned short*)(ws);               // 24 MB [p][b][c][n]
    float*          OP = (float*)(ws);                        // 16 MB (alias of D)
    unsigned short* Qt = (unsigned short*)(ws + 25165824);    // 1 MB (b,n,r)
    unsigned short* Kt = (unsigned short*)(ws + 26214400);    // 1 MB (b,n,r)
    unsigned short* V  = (unsigned short*)(ws + 27262976);    // 1 MB (b,r,n)
    float*          LP = (float*)(ws + 28311552);             // 1 MB
    unsigned short* FMt= (unsigned short*)(ws + 29360128);    // 1 MB (b,n,r)

    hipLaunchKernelGGL(k_dw, dim3(CC, BB), dim3(256), 0, stream, x,
                       (const float*)d_in[1], (const float*)d_in[2],
                       (const float*)d_in[5], (const float*)d_in[6],
                       (const float*)d_in[9], (const float*)d_in[10], Dq);
    hipLaunchKernelGGL(k_pw, dim3(32, 3, BB), dim3(256), 0, stream, Dq,
                       (const float*)d_in[3], (const float*)d_in[4],
                       (const float*)d_in[7], (const float*)d_in[8],
                       (const float*)d_in[11], (const float*)d_in[12],
                       V, Qt, Kt);
    hipLaunchKernelGGL(k_attn, dim3(32, NCHUNK, BB), dim3(256), 0, stream, Qt, Kt, V, OP, LP);
    hipLaunchKernelGGL(k_merge, dim3(128, BB), dim3(64), 0, stream, OP, LP, FMt);
    hipLaunchKernelGGL(k_convout, dim3(32, 8, BB), dim3(256), 0, stream,
                       x, FMt, (const float*)d_in[13], (const float*)d_in[14], (float*)d_out);
}

// Round 8
// 143.344 us; speedup vs baseline: 2.7655x; 1.0105x over previous
//
#include <hip/hip_runtime.h>
#include <stdint.h>

#define BB 4
#define CC 256
#define NN 4096   // H*W = 64*64
#define RR 32
#define NCHUNK 8
#define JSTEPS (NN / NCHUNK / 32)   // 16
#define CSIZE  (NN / NCHUNK)        // 512

typedef __attribute__((ext_vector_type(8)))  short  short8;   // 8 bf16 (MFMA A/B frag)
typedef __attribute__((ext_vector_type(4)))  short  short4v;  // 4 bf16 = 8B
typedef __attribute__((ext_vector_type(16))) float  floatx16; // MFMA C/D frag

#if defined(__has_builtin)
#if __has_builtin(__builtin_amdgcn_cvt_pk_bf16_f32)
#define HAVE_PK_BF16 1
#endif
#endif

#ifdef HAVE_PK_BF16
typedef __attribute__((ext_vector_type(2))) __bf16 bf16x2;
#endif

static __device__ __forceinline__ unsigned short f2bf_sw(float f) {
    union { float f; unsigned int u; } v; v.f = f;
    unsigned int u = v.u;
    u += 0x7fffu + ((u >> 16) & 1u);
    return (unsigned short)(u >> 16);
}

// pack two fp32 -> bf16x2 in one HW inst (lo = a, hi = b)
static __device__ __forceinline__ unsigned int pk_bf16(float a, float b) {
#ifdef HAVE_PK_BF16
    bf16x2 r = __builtin_amdgcn_cvt_pk_bf16_f32(a, b);
    unsigned int u; __builtin_memcpy(&u, &r, 4); return u;
#else
    return (unsigned int)f2bf_sw(a) | ((unsigned int)f2bf_sw(b) << 16);
#endif
}

static __device__ __forceinline__ unsigned short f2bf(float f) {
#ifdef HAVE_PK_BF16
    return (unsigned short)(pk_bf16(f, 0.f) & 0xffffu);
#else
    return f2bf_sw(f);
#endif
}

static __device__ __forceinline__ float exp2_fast(float x) {
#if __has_builtin(__builtin_amdgcn_exp2f)
    return __builtin_amdgcn_exp2f(x);
#else
    return exp2f(x);
#endif
}

// ---------------- K1: depthwise 3x3, all 3 dilations -> D bf16 --------------
// grid (C, B), block 256 = 4 waves; wave = 16-h strip, lane = w. 26 x-rows in
// registers (x read exactly once); horizontal taps via shfl (CSE'd per phase).
// D layout: [p][b][c][n] bf16.
__global__ __launch_bounds__(256, 4) void k_dw(
    const float* __restrict__ x,
    const float* __restrict__ w1, const float* __restrict__ b1,
    const float* __restrict__ w2, const float* __restrict__ b2,
    const float* __restrict__ w3, const float* __restrict__ b3,
    unsigned short* __restrict__ Dq)
{
    int t = threadIdx.x, lane = t & 63, wv = t >> 6;
    int c = blockIdx.x, b = blockIdx.y;
    int hb = wv * 16;
    const float* xc = x + ((size_t)(b * CC + c)) * NN;
    float row[26];
    #pragma unroll
    for (int k = 0; k < 26; k++) {
        int rr = hb - 5 + k;
        int rc = rr < 0 ? 0 : (rr > 63 ? 63 : rr);
        float v = xc[rc * 64 + lane];
        row[k] = (rr >= 0 && rr <= 63) ? v : 0.f;
    }
    const float* DWW[3] = {w1, w2, w3};
    const float* DWB[3] = {b1, b2, b3};
    #pragma unroll
    for (int p = 0; p < 3; p++) {
        const int d = (p == 0) ? 1 : (p == 1 ? 3 : 5);
        float wt[9];
        #pragma unroll
        for (int q = 0; q < 9; q++) wt[q] = DWW[p][c * 9 + q];
        float bias = DWB[p][c];
        bool okl = lane >= d, okr = lane < 64 - d;
        int lml = okl ? lane - d : 0;
        int lpr = okr ? lane + d : 63;
        float sm[26], sp[26];
        #pragma unroll
        for (int k = 5 - d; k <= 20 + d; k++) {
            float a = __shfl(row[k], lml, 64); sm[k] = okl ? a : 0.f;
            float q2 = __shfl(row[k], lpr, 64); sp[k] = okr ? q2 : 0.f;
        }
        unsigned short* Dp = Dq + (((size_t)p * BB + b) * CC + c) * NN;
        #pragma unroll
        for (int hl = 0; hl < 16; hl++) {
            int k0 = hl + 5 - d, k1 = hl + 5, k2 = hl + 5 + d;
            float o = bias
                + wt[0] * sm[k0] + wt[1] * row[k0] + wt[2] * sp[k0]
                + wt[3] * sm[k1] + wt[4] * row[k1] + wt[5] * sp[k1]
                + wt[6] * sm[k2] + wt[7] * row[k2] + wt[8] * sp[k2];
            Dp[(hb + hl) * 64 + lane] = f2bf(o);
        }
    }
}

// ---------------- K2: pointwise C->R as MFMA GEMM ---------------------------
// grid (32 ntiles of 128 n, 3 p, B), block 256 = 4 waves; wave = 32r x 32n,
// K=256 = 16 x mfma_32x32x16. A = pw bf16 (LDS-staged), B = D[c][n] gathers.
__global__ __launch_bounds__(256, 4) void k_pw(
    const unsigned short* __restrict__ Dq,
    const float* __restrict__ p1, const float* __restrict__ pb1,
    const float* __restrict__ p2, const float* __restrict__ pb2,
    const float* __restrict__ p3, const float* __restrict__ pb3,
    unsigned short* __restrict__ V, unsigned short* __restrict__ Qt,
    unsigned short* __restrict__ Kt)
{
    __shared__ unsigned short PW[32 * 264];        // pw bf16, row stride 264 (16B-aligned)
    __shared__ unsigned short Lt[4][32][40];       // per-wave [n][r] transpose buffer
    int t = threadIdx.x, lane = t & 63, l31 = lane & 31, h = lane >> 5, wv = t >> 6;
    int ntile = blockIdx.x, p = blockIdx.y, b = blockIdx.z;
    const float* pw  = (p == 0) ? p1  : (p == 1 ? p2  : p3);
    const float* pwb = (p == 0) ? pb1 : (p == 1 ? pb2 : pb3);

    // stage pw -> bf16 LDS: thread r = t>>3, 32-col block (t&7)*32
    {
        int r = t >> 3, cb0 = (t & 7) * 32;
        const float4* src = (const float4*)(pw + r * CC + cb0);
        #pragma unroll
        for (int g = 0; g < 8; g++) {
            float4 f = src[g];
            union { short4v s; unsigned int u[2]; } s4;
            s4.u[0] = pk_bf16(f.x, f.y);
            s4.u[1] = pk_bf16(f.z, f.w);
            *(short4v*)&PW[r * 264 + cb0 + g * 4] = s4.s;
        }
    }
    __syncthreads();

    int n = ntile * 128 + wv * 32 + l31;
    // B base: c = 8h folded in; element j of frag kt -> c = kt*16 + 8h + j
    const unsigned short* Dn = Dq + (((size_t)p * BB + b) * CC + 8 * h) * NN + n;
    floatx16 acc = {};
    #pragma unroll 4
    for (int kt = 0; kt < 16; kt++) {
        short8 af = *(const short8*)&PW[l31 * 264 + kt * 16 + 8 * h];
        short8 bf;
        #pragma unroll
        for (int j = 0; j < 8; j++) bf[j] = (short)Dn[(size_t)(kt * 16 + j) * NN];
        acc = __builtin_amdgcn_mfma_f32_32x32x16_bf16(af, bf, acc, 0, 0, 0);
    }

    if (p == 0) {
        #pragma unroll
        for (int rr = 0; rr < 16; rr++) {
            int r = (rr & 3) + 8 * (rr >> 2) + 4 * h;          // C/D row mapping
            V[((size_t)(b * RR + r)) * NN + n] = f2bf(acc[rr] + pwb[r]);  // V[b][r][n]
        }
    } else {
        const float sc = (p == 1) ? 1.4426950408889634f : 1.f; // Q *= log2e
        unsigned short* outp = (p == 1) ? Qt : Kt;
        #pragma unroll
        for (int rr = 0; rr < 16; rr++) {
            int r = (rr & 3) + 8 * (rr >> 2) + 4 * h;
            Lt[wv][l31][r] = f2bf((acc[rr] + pwb[r]) * sc);
        }
        __threadfence_block();   // order wave-local LDS write->read (lockstep lanes)
        unsigned short* orow = outp + ((size_t)b * NN + n) * RR + h * 16;
        short8 lo = *(const short8*)&Lt[wv][l31][h * 16];
        *(short8*)orow = lo;                                   // [b][n][r], 32B/lane
        short8 hi = *(const short8*)&Lt[wv][l31][h * 16 + 8];
        *(short8*)(orow + 8) = hi;
    }
}

// ---------------- K3: fused attention, double-buffered LDS V ----------------
// grid (32, NCHUNK, B), block 256 = 4 waves (4 itiles, same chunk -> shared V).
__global__ __launch_bounds__(256, 4) void k_attn(
    const unsigned short* __restrict__ Qt, const unsigned short* __restrict__ Kt,
    const unsigned short* __restrict__ V, float* __restrict__ OP, float* __restrict__ LP)
{
    __shared__ unsigned short Vt[2][32][36];   // double buffer, 2-way-free stride
    int t = threadIdx.x;
    int wave = t >> 6, lane = t & 63, l31 = lane & 31, h = lane >> 5;
    int itile = blockIdx.x * 4 + wave;
    int chunk = blockIdx.y;
    int b = blockIdx.z;
    int i = itile * 32 + l31;

    const short8* qrow = (const short8*)(Qt + ((size_t)b * NN + i) * RR);
    short8 q1 = qrow[h], q2 = qrow[2 + h];

    const unsigned short* Kb = Kt + (size_t)b * NN * RR;
    const unsigned short* Vb = V + (size_t)b * RR * NN;

    int sr = t >> 3, sc = t & 7;
    const unsigned short* vsrc = Vb + (size_t)sr * NN + chunk * CSIZE + sc * 4;

    floatx16 acc = {};
    float lacc = 0.f;

    // prologue: stage step-0 V tile, prefetch step-1 V and step-0 K
    *(short4v*)(&Vt[0][sr][sc * 4]) = *(const short4v*)vsrc;
    short4v vnext = *(const short4v*)(vsrc + 32);
    const short8* krow0 = (const short8*)(Kb + (size_t)(chunk * CSIZE + l31) * RR);
    short8 ka1 = krow0[h], ka2 = krow0[2 + h];
    __syncthreads();

    for (int js = 0; js < JSTEPS; js++) {
        int cur = js & 1;
        if (js + 1 < JSTEPS) *(short4v*)(&Vt[1 - cur][sr][sc * 4]) = vnext;
        if (js + 2 < JSTEPS) vnext = *(const short4v*)(vsrc + (js + 2) * 32);

        floatx16 st = {};
        st = __builtin_amdgcn_mfma_f32_32x32x16_bf16(ka1, q1, st, 0, 0, 0);
        st = __builtin_amdgcn_mfma_f32_32x32x16_bf16(ka2, q2, st, 0, 0, 0);
        int jn = (js + 1 < JSTEPS) ? js + 1 : js;
        const short8* krow = (const short8*)(Kb + (size_t)(chunk * CSIZE + jn * 32 + l31) * RR);
        ka1 = krow[h]; ka2 = krow[2 + h];

        float p[16];
        #pragma unroll
        for (int r = 0; r < 16; r++) { p[r] = exp2_fast(st[r]); lacc += p[r]; }
        union { short8 s; unsigned int u[4]; } pa1, pa2;
        #pragma unroll
        for (int r = 0; r < 8; r += 2) {
            pa1.u[r >> 1] = pk_bf16(p[r], p[r + 1]);
            pa2.u[r >> 1] = pk_bf16(p[r + 8], p[r + 9]);
        }
        const unsigned short* vrow = &Vt[cur][l31][0];
        short4v v0 = *(const short4v*)(vrow + 4 * h);
        short4v v1 = *(const short4v*)(vrow + 8 + 4 * h);
        short4v v2 = *(const short4v*)(vrow + 16 + 4 * h);
        short4v v3 = *(const short4v*)(vrow + 24 + 4 * h);
        short8 vb1, vb2;
        #pragma unroll
        for (int q = 0; q < 4; q++) {
            vb1[q] = v0[q]; vb1[q + 4] = v1[q];
            vb2[q] = v2[q]; vb2[q + 4] = v3[q];
        }
        acc = __builtin_amdgcn_mfma_f32_32x32x16_bf16(pa1.s, vb1, acc, 0, 0, 0);
        acc = __builtin_amdgcn_mfma_f32_32x32x16_bf16(pa2.s, vb2, acc, 0, 0, 0);
        __syncthreads();   // reads of Vt[cur] done; Vt[1-cur] visible for js+1
    }
    size_t slot = ((size_t)(b * 128 + itile) * NCHUNK + chunk) * 64 + lane;
    float* op = OP + slot * 16;
    #pragma unroll
    for (int r = 0; r < 16; r++) op[r] = acc[r];
    LP[slot] = lacc;
}

// ---------------- K4: fused merge + 1x1 conv R->C + residual ----------------
// grid (128 itiles, B), block 256. Reduce OP chunks in-register -> Ft tile in
// LDS (bf16 [n32][r32]) -> 8x mfma vs LDS-staged cw -> out = x + conv + bias.
__global__ __launch_bounds__(256, 4) void k_out(
    const float* __restrict__ x, const float* __restrict__ OP,
    const float* __restrict__ LP, const float* __restrict__ cw,
    const float* __restrict__ cb, float* __restrict__ out)
{
    __shared__ float linv[32];
    __shared__ unsigned short Ft[32][36];     // [n_local][r], 2-way-free stride
    __shared__ unsigned short CW[256 * 36];   // cw bf16, row stride 36
    int t = threadIdx.x, lane = t & 63, l31 = lane & 31, h = lane >> 5, wv = t >> 6;
    int itile = blockIdx.x, b = blockIdx.y;
    size_t base = (size_t)(b * 128 + itile) * NCHUNK;

    // stage cw -> bf16 LDS: thread t owns row co=t (32 floats)
    {
        const float4* src = (const float4*)(cw + (size_t)t * RR);
        #pragma unroll
        for (int g = 0; g < 8; g++) {
            float4 f = src[g];
            union { short4v s; unsigned int u[2]; } s4;
            s4.u[0] = pk_bf16(f.x, f.y);
            s4.u[1] = pk_bf16(f.z, f.w);
            *(short4v*)&CW[t * 36 + g * 4] = s4.s;
        }
    }
    // reduce OP chunks: thread (ln=lane, g=wv) owns regs 4g..4g+3
    int g = wv;
    float s0 = 0.f, s1 = 0.f, s2 = 0.f, s3 = 0.f;
    #pragma unroll
    for (int ch = 0; ch < NCHUNK; ch++) {
        const float4 v = *(const float4*)(OP + ((base + ch) * 64 + lane) * 16 + 4 * g);
        s0 += v.x; s1 += v.y; s2 += v.z; s3 += v.w;
    }
    // softmax denominators (rows i_local = t<32)
    if (t < 32) {
        float sl = 0.f;
        #pragma unroll
        for (int ch = 0; ch < NCHUNK; ch++) {
            sl += LP[(base + ch) * 64 + t] + LP[(base + ch) * 64 + t + 32];
        }
        linv[t] = 1.f / sl;
    }
    __syncthreads();   // linv + CW ready
    {
        float sv[4] = {s0, s1, s2, s3};
        #pragma unroll
        for (int j = 0; j < 4; j++) {
            int reg = 4 * g + j;
            int il = (reg & 3) + 8 * (reg >> 2) + 4 * h;   // C/D row mapping
            Ft[il][l31] = f2bf(sv[j] * linv[il]);          // r = l31 channel
        }
    }
    __syncthreads();   // Ft ready
    // convout: wave wv does co-tiles 2wv, 2wv+1
    #pragma unroll
    for (int cti = 0; cti < 2; cti++) {
        int co0 = (wv * 2 + cti) * 32;
        const unsigned short* arow = &CW[(co0 + l31) * 36 + 8 * h];
        union { short8 s; short4v hh[2]; } a1, a2, b1, b2;
        a1.hh[0] = *(const short4v*)arow;
        a1.hh[1] = *(const short4v*)(arow + 4);
        a2.hh[0] = *(const short4v*)(arow + 16);
        a2.hh[1] = *(const short4v*)(arow + 20);
        const unsigned short* brow = &Ft[l31][8 * h];
        b1.hh[0] = *(const short4v*)brow;
        b1.hh[1] = *(const short4v*)(brow + 4);
        b2.hh[0] = *(const short4v*)(brow + 16);
        b2.hh[1] = *(const short4v*)(brow + 20);
        floatx16 acc = {};
        acc = __builtin_amdgcn_mfma_f32_32x32x16_bf16(a1.s, b1.s, acc, 0, 0, 0);
        acc = __builtin_amdgcn_mfma_f32_32x32x16_bf16(a2.s, b2.s, acc, 0, 0, 0);
        #pragma unroll
        for (int rr = 0; rr < 16; rr++) {
            int co = co0 + (rr & 3) + 8 * (rr >> 2) + 4 * h;
            size_t o = ((size_t)(b * CC + co)) * NN + itile * 32 + l31;
            out[o] = x[o] + acc[rr] + cb[co];
        }
    }
}

extern "C" void kernel_launch(void* const* d_in, const int* in_sizes, int n_in,
                              void* d_out, int out_size, void* d_ws, size_t ws_size,
                              hipStream_t stream) {
    const float* x = (const float*)d_in[0];
    char* ws = (char*)d_ws;
    // D (24 MB, dead after k_pw) aliases OP (16 MB, written by k_attn)
    unsigned short* Dq = (unsigned short*)(ws);               // 24 MB [p][b][c][n]
    float*          OP = (float*)(ws);                        // 16 MB (alias of D)
    unsigned short* Qt = (unsigned short*)(ws + 25165824);    // 1 MB (b,n,r)
    unsigned short* Kt = (unsigned short*)(ws + 26214400);    // 1 MB (b,n,r)
    unsigned short* V  = (unsigned short*)(ws + 27262976);    // 1 MB (b,r,n)
    float*          LP = (float*)(ws + 28311552);             // 1 MB

    hipLaunchKernelGGL(k_dw, dim3(CC, BB), dim3(256), 0, stream, x,
                       (const float*)d_in[1], (const float*)d_in[2],
                       (const float*)d_in[5], (const float*)d_in[6],
                       (const float*)d_in[9], (const float*)d_in[10], Dq);
    hipLaunchKernelGGL(k_pw, dim3(32, 3, BB), dim3(256), 0, stream, Dq,
                       (const float*)d_in[3], (const float*)d_in[4],
                       (const float*)d_in[7], (const float*)d_in[8],
                       (const float*)d_in[11], (const float*)d_in[12],
                       V, Qt, Kt);
    hipLaunchKernelGGL(k_attn, dim3(32, NCHUNK, BB), dim3(256), 0, stream, Qt, Kt, V, OP, LP);
    hipLaunchKernelGGL(k_out, dim3(128, BB), dim3(256), 0, stream,
                       x, OP, LP, (const float*)d_in[13], (const float*)d_in[14],
                       (float*)d_out);
}

// Round 9
// 141.762 us; speedup vs baseline: 2.7963x; 1.0112x over previous
//
#include <hip/hip_runtime.h>
#include <stdint.h>

#define BB 4
#define CC 256
#define NN 4096   // H*W = 64*64
#define RR 32
#define NCHUNK 8
#define JSTEPS (NN / NCHUNK / 32)   // 16
#define CSIZE  (NN / NCHUNK)        // 512

typedef __attribute__((ext_vector_type(8)))  short  short8;   // 8 bf16 (MFMA A/B frag)
typedef __attribute__((ext_vector_type(4)))  short  short4v;  // 4 bf16 = 8B
typedef __attribute__((ext_vector_type(16))) float  floatx16; // MFMA C/D frag

#if defined(__has_builtin)
#if __has_builtin(__builtin_amdgcn_cvt_pk_bf16_f32)
#define HAVE_PK_BF16 1
#endif
#endif

#ifdef HAVE_PK_BF16
typedef __attribute__((ext_vector_type(2))) __bf16 bf16x2;
#endif

static __device__ __forceinline__ unsigned short f2bf_sw(float f) {
    union { float f; unsigned int u; } v; v.f = f;
    unsigned int u = v.u;
    u += 0x7fffu + ((u >> 16) & 1u);
    return (unsigned short)(u >> 16);
}

// pack two fp32 -> bf16x2 in one HW inst (lo = a, hi = b)
static __device__ __forceinline__ unsigned int pk_bf16(float a, float b) {
#ifdef HAVE_PK_BF16
    bf16x2 r = __builtin_amdgcn_cvt_pk_bf16_f32(a, b);
    unsigned int u; __builtin_memcpy(&u, &r, 4); return u;
#else
    return (unsigned int)f2bf_sw(a) | ((unsigned int)f2bf_sw(b) << 16);
#endif
}

static __device__ __forceinline__ unsigned short f2bf(float f) {
#ifdef HAVE_PK_BF16
    return (unsigned short)(pk_bf16(f, 0.f) & 0xffffu);
#else
    return f2bf_sw(f);
#endif
}

static __device__ __forceinline__ float exp2_fast(float x) {
#if __has_builtin(__builtin_amdgcn_exp2f)
    return __builtin_amdgcn_exp2f(x);
#else
    return exp2f(x);
#endif
}

// ---------------- K1: depthwise 3x3, all 3 dilations -> D bf16 --------------
// grid (C, B), block 256 = 4 waves; wave = 16-h strip, lane = w. 26 x-rows in
// registers (x read exactly once); horizontal taps via shfl (CSE'd per phase).
// D layout: [p][b][c][n] bf16.
__global__ __launch_bounds__(256, 4) void k_dw(
    const float* __restrict__ x,
    const float* __restrict__ w1, const float* __restrict__ b1,
    const float* __restrict__ w2, const float* __restrict__ b2,
    const float* __restrict__ w3, const float* __restrict__ b3,
    unsigned short* __restrict__ Dq)
{
    int t = threadIdx.x, lane = t & 63, wv = t >> 6;
    int c = blockIdx.x, b = blockIdx.y;
    int hb = wv * 16;
    const float* xc = x + ((size_t)(b * CC + c)) * NN;
    float row[26];
    #pragma unroll
    for (int k = 0; k < 26; k++) {
        int rr = hb - 5 + k;
        int rc = rr < 0 ? 0 : (rr > 63 ? 63 : rr);
        float v = xc[rc * 64 + lane];
        row[k] = (rr >= 0 && rr <= 63) ? v : 0.f;
    }
    const float* DWW[3] = {w1, w2, w3};
    const float* DWB[3] = {b1, b2, b3};
    #pragma unroll
    for (int p = 0; p < 3; p++) {
        const int d = (p == 0) ? 1 : (p == 1 ? 3 : 5);
        float wt[9];
        #pragma unroll
        for (int q = 0; q < 9; q++) wt[q] = DWW[p][c * 9 + q];
        float bias = DWB[p][c];
        bool okl = lane >= d, okr = lane < 64 - d;
        int lml = okl ? lane - d : 0;
        int lpr = okr ? lane + d : 63;
        float sm[26], sp[26];
        #pragma unroll
        for (int k = 5 - d; k <= 20 + d; k++) {
            float a = __shfl(row[k], lml, 64); sm[k] = okl ? a : 0.f;
            float q2 = __shfl(row[k], lpr, 64); sp[k] = okr ? q2 : 0.f;
        }
        unsigned short* Dp = Dq + (((size_t)p * BB + b) * CC + c) * NN;
        #pragma unroll
        for (int hl = 0; hl < 16; hl++) {
            int k0 = hl + 5 - d, k1 = hl + 5, k2 = hl + 5 + d;
            float o = bias
                + wt[0] * sm[k0] + wt[1] * row[k0] + wt[2] * sp[k0]
                + wt[3] * sm[k1] + wt[4] * row[k1] + wt[5] * sp[k1]
                + wt[6] * sm[k2] + wt[7] * row[k2] + wt[8] * sp[k2];
            Dp[(hb + hl) * 64 + lane] = f2bf(o);
        }
    }
}

// ---------------- K2: pointwise C->R as MFMA GEMM, LDS-staged B -------------
// grid (32 ntiles of 128 n, 3 p, B), block 256 = 4 waves; wave = 32r x 32n.
// K=256 in two 128-c halves staged into LDS (coalesced b128 loads, b64 LDS
// writes); B-frags = conflict-free ds_read_u16 (stride 132: h-groups land on
// disjoint bank halves). A = pw bf16 (LDS-staged).
__global__ __launch_bounds__(256, 2) void k_pw(
    const unsigned short* __restrict__ Dq,
    const float* __restrict__ p1, const float* __restrict__ pb1,
    const float* __restrict__ p2, const float* __restrict__ pb2,
    const float* __restrict__ p3, const float* __restrict__ pb3,
    unsigned short* __restrict__ V, unsigned short* __restrict__ Qt,
    unsigned short* __restrict__ Kt)
{
    __shared__ unsigned short PW[32 * 264];        // pw bf16, row stride 264B-friendly
    __shared__ unsigned short Dt[128 * 132];       // D half-tile [c128][n128], pad 4
    __shared__ unsigned short Lt[4][32][40];       // per-wave [n][r] transpose buffer
    int t = threadIdx.x, lane = t & 63, l31 = lane & 31, h = lane >> 5, wv = t >> 6;
    int ntile = blockIdx.x, p = blockIdx.y, b = blockIdx.z;
    const float* pw  = (p == 0) ? p1  : (p == 1 ? p2  : p3);
    const float* pwb = (p == 0) ? pb1 : (p == 1 ? pb2 : pb3);

    // stage pw -> bf16 LDS: thread r = t>>3, 32-col block (t&7)*32
    {
        int r = t >> 3, cb0 = (t & 7) * 32;
        const float4* src = (const float4*)(pw + r * CC + cb0);
        #pragma unroll
        for (int g = 0; g < 8; g++) {
            float4 f = src[g];
            union { short4v s; unsigned int u[2]; } s4;
            s4.u[0] = pk_bf16(f.x, f.y);
            s4.u[1] = pk_bf16(f.z, f.w);
            *(short4v*)&PW[r * 264 + cb0 + g * 4] = s4.s;
        }
    }
    __syncthreads();

    int n = ntile * 128 + wv * 32 + l31;
    const size_t dbase = ((size_t)p * BB + b) * CC * (size_t)NN;
    int cr = t >> 1, nseg = (t & 1) * 64;          // staging: row cr, 64-n segment
    floatx16 acc = {};

    for (int hc = 0; hc < 2; hc++) {
        // bulk global load of this c-half's 128B/thread (coalesced, indep)
        const uint4* gsrc = (const uint4*)(Dq + dbase +
                            (size_t)(hc * 128 + cr) * NN + ntile * 128 + nseg);
        uint4 g[8];
        #pragma unroll
        for (int i = 0; i < 8; i++) g[i] = gsrc[i];
        __syncthreads();   // prior half's Dt reads complete
        {
            uint2* ldst = (uint2*)&Dt[cr * 132 + nseg];   // 8B-aligned (264B rows)
            #pragma unroll
            for (int i = 0; i < 8; i++) {
                union { uint4 q; uint2 d2[2]; } u; u.q = g[i];
                ldst[2 * i] = u.d2[0];
                ldst[2 * i + 1] = u.d2[1];
            }
        }
        __syncthreads();   // tile visible
        #pragma unroll
        for (int kt = 0; kt < 8; kt++) {
            short8 af = *(const short8*)&PW[l31 * 264 + hc * 128 + kt * 16 + 8 * h];
            short8 bf;
            #pragma unroll
            for (int j = 0; j < 8; j++)
                bf[j] = (short)Dt[(kt * 16 + 8 * h + j) * 132 + wv * 32 + l31];
            acc = __builtin_amdgcn_mfma_f32_32x32x16_bf16(af, bf, acc, 0, 0, 0);
        }
    }

    if (p == 0) {
        #pragma unroll
        for (int rr = 0; rr < 16; rr++) {
            int r = (rr & 3) + 8 * (rr >> 2) + 4 * h;          // C/D row mapping
            V[((size_t)(b * RR + r)) * NN + n] = f2bf(acc[rr] + pwb[r]);  // V[b][r][n]
        }
    } else {
        const float sc = (p == 1) ? 1.4426950408889634f : 1.f; // Q *= log2e
        unsigned short* outp = (p == 1) ? Qt : Kt;
        #pragma unroll
        for (int rr = 0; rr < 16; rr++) {
            int r = (rr & 3) + 8 * (rr >> 2) + 4 * h;
            Lt[wv][l31][r] = f2bf((acc[rr] + pwb[r]) * sc);
        }
        __threadfence_block();   // order wave-local LDS write->read (lockstep lanes)
        unsigned short* orow = outp + ((size_t)b * NN + n) * RR + h * 16;
        short8 lo = *(const short8*)&Lt[wv][l31][h * 16];
        *(short8*)orow = lo;                                   // [b][n][r], 32B/lane
        short8 hi = *(const short8*)&Lt[wv][l31][h * 16 + 8];
        *(short8*)(orow + 8) = hi;
    }
}

// ---------------- K3: fused attention, double-buffered LDS V ----------------
// grid (32, NCHUNK, B), block 256 = 4 waves (4 itiles, same chunk -> shared V).
__global__ __launch_bounds__(256, 4) void k_attn(
    const unsigned short* __restrict__ Qt, const unsigned short* __restrict__ Kt,
    const unsigned short* __restrict__ V, float* __restrict__ OP, float* __restrict__ LP)
{
    __shared__ unsigned short Vt[2][32][36];   // double buffer, 2-way-free stride
    int t = threadIdx.x;
    int wave = t >> 6, lane = t & 63, l31 = lane & 31, h = lane >> 5;
    int itile = blockIdx.x * 4 + wave;
    int chunk = blockIdx.y;
    int b = blockIdx.z;
    int i = itile * 32 + l31;

    const short8* qrow = (const short8*)(Qt + ((size_t)b * NN + i) * RR);
    short8 q1 = qrow[h], q2 = qrow[2 + h];

    const unsigned short* Kb = Kt + (size_t)b * NN * RR;
    const unsigned short* Vb = V + (size_t)b * RR * NN;

    int sr = t >> 3, sc = t & 7;
    const unsigned short* vsrc = Vb + (size_t)sr * NN + chunk * CSIZE + sc * 4;

    floatx16 acc = {};
    float lacc = 0.f;

    // prologue: stage step-0 V tile, prefetch step-1 V and step-0 K
    *(short4v*)(&Vt[0][sr][sc * 4]) = *(const short4v*)vsrc;
    short4v vnext = *(const short4v*)(vsrc + 32);
    const short8* krow0 = (const short8*)(Kb + (size_t)(chunk * CSIZE + l31) * RR);
    short8 ka1 = krow0[h], ka2 = krow0[2 + h];
    __syncthreads();

    for (int js = 0; js < JSTEPS; js++) {
        int cur = js & 1;
        if (js + 1 < JSTEPS) *(short4v*)(&Vt[1 - cur][sr][sc * 4]) = vnext;
        if (js + 2 < JSTEPS) vnext = *(const short4v*)(vsrc + (js + 2) * 32);

        floatx16 st = {};
        st = __builtin_amdgcn_mfma_f32_32x32x16_bf16(ka1, q1, st, 0, 0, 0);
        st = __builtin_amdgcn_mfma_f32_32x32x16_bf16(ka2, q2, st, 0, 0, 0);
        int jn = (js + 1 < JSTEPS) ? js + 1 : js;
        const short8* krow = (const short8*)(Kb + (size_t)(chunk * CSIZE + jn * 32 + l31) * RR);
        ka1 = krow[h]; ka2 = krow[2 + h];

        float p[16];
        #pragma unroll
        for (int r = 0; r < 16; r++) { p[r] = exp2_fast(st[r]); lacc += p[r]; }
        union { short8 s; unsigned int u[4]; } pa1, pa2;
        #pragma unroll
        for (int r = 0; r < 8; r += 2) {
            pa1.u[r >> 1] = pk_bf16(p[r], p[r + 1]);
            pa2.u[r >> 1] = pk_bf16(p[r + 8], p[r + 9]);
        }
        const unsigned short* vrow = &Vt[cur][l31][0];
        short4v v0 = *(const short4v*)(vrow + 4 * h);
        short4v v1 = *(const short4v*)(vrow + 8 + 4 * h);
        short4v v2 = *(const short4v*)(vrow + 16 + 4 * h);
        short4v v3 = *(const short4v*)(vrow + 24 + 4 * h);
        short8 vb1, vb2;
        #pragma unroll
        for (int q = 0; q < 4; q++) {
            vb1[q] = v0[q]; vb1[q + 4] = v1[q];
            vb2[q] = v2[q]; vb2[q + 4] = v3[q];
        }
        acc = __builtin_amdgcn_mfma_f32_32x32x16_bf16(pa1.s, vb1, acc, 0, 0, 0);
        acc = __builtin_amdgcn_mfma_f32_32x32x16_bf16(pa2.s, vb2, acc, 0, 0, 0);
        __syncthreads();   // reads of Vt[cur] done; Vt[1-cur] visible for js+1
    }
    size_t slot = ((size_t)(b * 128 + itile) * NCHUNK + chunk) * 64 + lane;
    float* op = OP + slot * 16;
    #pragma unroll
    for (int r = 0; r < 16; r++) op[r] = acc[r];
    LP[slot] = lacc;
}

// ---------------- K4: fused merge + 1x1 conv R->C + residual ----------------
// grid (128 itiles, B), block 256. Reduce OP chunks in-register -> Ft tile in
// LDS (bf16 [n32][r32]) -> 8x mfma vs LDS-staged cw -> out = x + conv + bias.
__global__ __launch_bounds__(256, 4) void k_out(
    const float* __restrict__ x, const float* __restrict__ OP,
    const float* __restrict__ LP, const float* __restrict__ cw,
    const float* __restrict__ cb, float* __restrict__ out)
{
    __shared__ float linv[32];
    __shared__ unsigned short Ft[32][36];     // [n_local][r], 2-way-free stride
    __shared__ unsigned short CW[256 * 36];   // cw bf16, row stride 36
    int t = threadIdx.x, lane = t & 63, l31 = lane & 31, h = lane >> 5, wv = t >> 6;
    int itile = blockIdx.x, b = blockIdx.y;
    size_t base = (size_t)(b * 128 + itile) * NCHUNK;

    // stage cw -> bf16 LDS: thread t owns row co=t (32 floats)
    {
        const float4* src = (const float4*)(cw + (size_t)t * RR);
        #pragma unroll
        for (int g = 0; g < 8; g++) {
            float4 f = src[g];
            union { short4v s; unsigned int u[2]; } s4;
            s4.u[0] = pk_bf16(f.x, f.y);
            s4.u[1] = pk_bf16(f.z, f.w);
            *(short4v*)&CW[t * 36 + g * 4] = s4.s;
        }
    }
    // reduce OP chunks: thread (ln=lane, g=wv) owns regs 4g..4g+3
    int g = wv;
    float s0 = 0.f, s1 = 0.f, s2 = 0.f, s3 = 0.f;
    #pragma unroll
    for (int ch = 0; ch < NCHUNK; ch++) {
        const float4 v = *(const float4*)(OP + ((base + ch) * 64 + lane) * 16 + 4 * g);
        s0 += v.x; s1 += v.y; s2 += v.z; s3 += v.w;
    }
    // softmax denominators (rows i_local = t<32)
    if (t < 32) {
        float sl = 0.f;
        #pragma unroll
        for (int ch = 0; ch < NCHUNK; ch++) {
            sl += LP[(base + ch) * 64 + t] + LP[(base + ch) * 64 + t + 32];
        }
        linv[t] = 1.f / sl;
    }
    __syncthreads();   // linv + CW ready
    {
        float sv[4] = {s0, s1, s2, s3};
        #pragma unroll
        for (int j = 0; j < 4; j++) {
            int reg = 4 * g + j;
            int il = (reg & 3) + 8 * (reg >> 2) + 4 * h;   // C/D row mapping
            Ft[il][l31] = f2bf(sv[j] * linv[il]);          // r = l31 channel
        }
    }
    __syncthreads();   // Ft ready
    // convout: wave wv does co-tiles 2wv, 2wv+1
    #pragma unroll
    for (int cti = 0; cti < 2; cti++) {
        int co0 = (wv * 2 + cti) * 32;
        const unsigned short* arow = &CW[(co0 + l31) * 36 + 8 * h];
        union { short8 s; short4v hh[2]; } a1, a2, b1, b2;
        a1.hh[0] = *(const short4v*)arow;
        a1.hh[1] = *(const short4v*)(arow + 4);
        a2.hh[0] = *(const short4v*)(arow + 16);
        a2.hh[1] = *(const short4v*)(arow + 20);
        const unsigned short* brow = &Ft[l31][8 * h];
        b1.hh[0] = *(const short4v*)brow;
        b1.hh[1] = *(const short4v*)(brow + 4);
        b2.hh[0] = *(const short4v*)(brow + 16);
        b2.hh[1] = *(const short4v*)(brow + 20);
        floatx16 acc = {};
        acc = __builtin_amdgcn_mfma_f32_32x32x16_bf16(a1.s, b1.s, acc, 0, 0, 0);
        acc = __builtin_amdgcn_mfma_f32_32x32x16_bf16(a2.s, b2.s, acc, 0, 0, 0);
        #pragma unroll
        for (int rr = 0; rr < 16; rr++) {
            int co = co0 + (rr & 3) + 8 * (rr >> 2) + 4 * h;
            size_t o = ((size_t)(b * CC + co)) * NN + itile * 32 + l31;
            out[o] = x[o] + acc[rr] + cb[co];
        }
    }
}

extern "C" void kernel_launch(void* const* d_in, const int* in_sizes, int n_in,
                              void* d_out, int out_size, void* d_ws, size_t ws_size,
                              hipStream_t stream) {
    const float* x = (const float*)d_in[0];
    char* ws = (char*)d_ws;
    // D (24 MB, dead after k_pw) aliases OP (16 MB, written by k_attn)
    unsigned short* Dq = (unsigned short*)(ws);               // 24 MB [p][b][c][n]
    float*          OP = (float*)(ws);                        // 16 MB (alias of D)
    unsigned short* Qt = (unsigned short*)(ws + 25165824);    // 1 MB (b,n,r)
    unsigned short* Kt = (unsigned short*)(ws + 26214400);    // 1 MB (b,n,r)
    unsigned short* V  = (unsigned short*)(ws + 27262976);    // 1 MB (b,r,n)
    float*          LP = (float*)(ws + 28311552);             // 1 MB

    hipLaunchKernelGGL(k_dw, dim3(CC, BB), dim3(256), 0, stream, x,
                       (const float*)d_in[1], (const float*)d_in[2],
                       (const float*)d_in[5], (const float*)d_in[6],
                       (const float*)d_in[9], (const float*)d_in[10], Dq);
    hipLaunchKernelGGL(k_pw, dim3(32, 3, BB), dim3(256), 0, stream, Dq,
                       (const float*)d_in[3], (const float*)d_in[4],
                       (const float*)d_in[7], (const float*)d_in[8],
                       (const float*)d_in[11], (const float*)d_in[12],
                       V, Qt, Kt);
    hipLaunchKernelGGL(k_attn, dim3(32, NCHUNK, BB), dim3(256), 0, stream, Qt, Kt, V, OP, LP);
    hipLaunchKernelGGL(k_out, dim3(128, BB), dim3(256), 0, stream,
                       x, OP, LP, (const float*)d_in[13], (const float*)d_in[14],
                       (float*)d_out);
}

// Round 10
// 141.557 us; speedup vs baseline: 2.8004x; 1.0015x over previous
//
#include <hip/hip_runtime.h>
#include <stdint.h>

#define BB 4
#define CC 256
#define NN 4096   // H*W = 64*64
#define RR 32
#define NCHUNK 8
#define JSTEPS (NN / NCHUNK / 32)   // 16
#define CSIZE  (NN / NCHUNK)        // 512

typedef __attribute__((ext_vector_type(8)))  short  short8;   // 8 bf16 (MFMA A/B frag)
typedef __attribute__((ext_vector_type(4)))  short  short4v;  // 4 bf16 = 8B
typedef __attribute__((ext_vector_type(16))) float  floatx16; // MFMA C/D frag

#if defined(__has_builtin)
#if __has_builtin(__builtin_amdgcn_cvt_pk_bf16_f32)
#define HAVE_PK_BF16 1
#endif
#endif

#ifdef HAVE_PK_BF16
typedef __attribute__((ext_vector_type(2))) __bf16 bf16x2;
#endif

static __device__ __forceinline__ unsigned short f2bf_sw(float f) {
    union { float f; unsigned int u; } v; v.f = f;
    unsigned int u = v.u;
    u += 0x7fffu + ((u >> 16) & 1u);
    return (unsigned short)(u >> 16);
}

// pack two fp32 -> bf16x2 in one HW inst (lo = a, hi = b)
static __device__ __forceinline__ unsigned int pk_bf16(float a, float b) {
#ifdef HAVE_PK_BF16
    bf16x2 r = __builtin_amdgcn_cvt_pk_bf16_f32(a, b);
    unsigned int u; __builtin_memcpy(&u, &r, 4); return u;
#else
    return (unsigned int)f2bf_sw(a) | ((unsigned int)f2bf_sw(b) << 16);
#endif
}

static __device__ __forceinline__ unsigned short f2bf(float f) {
#ifdef HAVE_PK_BF16
    return (unsigned short)(pk_bf16(f, 0.f) & 0xffffu);
#else
    return f2bf_sw(f);
#endif
}

static __device__ __forceinline__ float bf2f(unsigned short u) {
    union { unsigned int u; float f; } v; v.u = ((unsigned int)u) << 16;
    return v.f;
}

static __device__ __forceinline__ float exp2_fast(float x) {
#if __has_builtin(__builtin_amdgcn_exp2f)
    return __builtin_amdgcn_exp2f(x);
#else
    return exp2f(x);
#endif
}

// ---------------- K1: depthwise 3x3, all 3 dilations -> D bf16 --------------
// grid (C, B), block 256 = 4 waves; wave = 16-h strip, lane = w. 26 x-rows in
// registers (x read exactly once); horizontal taps via shfl (CSE'd per phase).
// D layout: [p][b][c][n] bf16.
__global__ __launch_bounds__(256, 4) void k_dw(
    const float* __restrict__ x,
    const float* __restrict__ w1, const float* __restrict__ b1,
    const float* __restrict__ w2, const float* __restrict__ b2,
    const float* __restrict__ w3, const float* __restrict__ b3,
    unsigned short* __restrict__ Dq)
{
    int t = threadIdx.x, lane = t & 63, wv = t >> 6;
    int c = blockIdx.x, b = blockIdx.y;
    int hb = wv * 16;
    const float* xc = x + ((size_t)(b * CC + c)) * NN;
    float row[26];
    #pragma unroll
    for (int k = 0; k < 26; k++) {
        int rr = hb - 5 + k;
        int rc = rr < 0 ? 0 : (rr > 63 ? 63 : rr);
        float v = xc[rc * 64 + lane];
        row[k] = (rr >= 0 && rr <= 63) ? v : 0.f;
    }
    const float* DWW[3] = {w1, w2, w3};
    const float* DWB[3] = {b1, b2, b3};
    #pragma unroll
    for (int p = 0; p < 3; p++) {
        const int d = (p == 0) ? 1 : (p == 1 ? 3 : 5);
        float wt[9];
        #pragma unroll
        for (int q = 0; q < 9; q++) wt[q] = DWW[p][c * 9 + q];
        float bias = DWB[p][c];
        bool okl = lane >= d, okr = lane < 64 - d;
        int lml = okl ? lane - d : 0;
        int lpr = okr ? lane + d : 63;
        float sm[26], sp[26];
        #pragma unroll
        for (int k = 5 - d; k <= 20 + d; k++) {
            float a = __shfl(row[k], lml, 64); sm[k] = okl ? a : 0.f;
            float q2 = __shfl(row[k], lpr, 64); sp[k] = okr ? q2 : 0.f;
        }
        unsigned short* Dp = Dq + (((size_t)p * BB + b) * CC + c) * NN;
        #pragma unroll
        for (int hl = 0; hl < 16; hl++) {
            int k0 = hl + 5 - d, k1 = hl + 5, k2 = hl + 5 + d;
            float o = bias
                + wt[0] * sm[k0] + wt[1] * row[k0] + wt[2] * sp[k0]
                + wt[3] * sm[k1] + wt[4] * row[k1] + wt[5] * sp[k1]
                + wt[6] * sm[k2] + wt[7] * row[k2] + wt[8] * sp[k2];
            Dp[(hb + hl) * 64 + lane] = f2bf(o);
        }
    }
}

// ---------------- K2: pointwise C->R as MFMA GEMM, LDS-staged B -------------
// grid (32 ntiles of 128 n, 3 p, B), block 256 = 4 waves; wave = 32r x 32n.
// K=256 in two 128-c halves staged into LDS; A = pw bf16 (LDS-staged).
__global__ __launch_bounds__(256, 2) void k_pw(
    const unsigned short* __restrict__ Dq,
    const float* __restrict__ p1, const float* __restrict__ pb1,
    const float* __restrict__ p2, const float* __restrict__ pb2,
    const float* __restrict__ p3, const float* __restrict__ pb3,
    unsigned short* __restrict__ V, unsigned short* __restrict__ Qt,
    unsigned short* __restrict__ Kt)
{
    __shared__ unsigned short PW[32 * 264];        // pw bf16, row stride 264
    __shared__ unsigned short Dt[128 * 132];       // D half-tile [c128][n128], pad 4
    __shared__ unsigned short Lt[4][32][40];       // per-wave [n][r] transpose buffer
    int t = threadIdx.x, lane = t & 63, l31 = lane & 31, h = lane >> 5, wv = t >> 6;
    int ntile = blockIdx.x, p = blockIdx.y, b = blockIdx.z;
    const float* pw  = (p == 0) ? p1  : (p == 1 ? p2  : p3);
    const float* pwb = (p == 0) ? pb1 : (p == 1 ? pb2 : pb3);

    // stage pw -> bf16 LDS: thread r = t>>3, 32-col block (t&7)*32
    {
        int r = t >> 3, cb0 = (t & 7) * 32;
        const float4* src = (const float4*)(pw + r * CC + cb0);
        #pragma unroll
        for (int g = 0; g < 8; g++) {
            float4 f = src[g];
            union { short4v s; unsigned int u[2]; } s4;
            s4.u[0] = pk_bf16(f.x, f.y);
            s4.u[1] = pk_bf16(f.z, f.w);
            *(short4v*)&PW[r * 264 + cb0 + g * 4] = s4.s;
        }
    }
    __syncthreads();

    int n = ntile * 128 + wv * 32 + l31;
    const size_t dbase = ((size_t)p * BB + b) * CC * (size_t)NN;
    int cr = t >> 1, nseg = (t & 1) * 64;          // staging: row cr, 64-n segment
    floatx16 acc = {};

    for (int hc = 0; hc < 2; hc++) {
        // bulk global load of this c-half's 128B/thread (coalesced, indep)
        const uint4* gsrc = (const uint4*)(Dq + dbase +
                            (size_t)(hc * 128 + cr) * NN + ntile * 128 + nseg);
        uint4 g[8];
        #pragma unroll
        for (int i = 0; i < 8; i++) g[i] = gsrc[i];
        __syncthreads();   // prior half's Dt reads complete
        {
            uint2* ldst = (uint2*)&Dt[cr * 132 + nseg];   // 8B-aligned (264B rows)
            #pragma unroll
            for (int i = 0; i < 8; i++) {
                union { uint4 q; uint2 d2[2]; } u; u.q = g[i];
                ldst[2 * i] = u.d2[0];
                ldst[2 * i + 1] = u.d2[1];
            }
        }
        __syncthreads();   // tile visible
        #pragma unroll
        for (int kt = 0; kt < 8; kt++) {
            short8 af = *(const short8*)&PW[l31 * 264 + hc * 128 + kt * 16 + 8 * h];
            short8 bf;
            #pragma unroll
            for (int j = 0; j < 8; j++)
                bf[j] = (short)Dt[(kt * 16 + 8 * h + j) * 132 + wv * 32 + l31];
            acc = __builtin_amdgcn_mfma_f32_32x32x16_bf16(af, bf, acc, 0, 0, 0);
        }
    }

    if (p == 0) {
        #pragma unroll
        for (int rr = 0; rr < 16; rr++) {
            int r = (rr & 3) + 8 * (rr >> 2) + 4 * h;          // C/D row mapping
            V[((size_t)(b * RR + r)) * NN + n] = f2bf(acc[rr] + pwb[r]);  // V[b][r][n]
        }
    } else {
        const float sc = (p == 1) ? 1.4426950408889634f : 1.f; // Q *= log2e
        unsigned short* outp = (p == 1) ? Qt : Kt;
        #pragma unroll
        for (int rr = 0; rr < 16; rr++) {
            int r = (rr & 3) + 8 * (rr >> 2) + 4 * h;
            Lt[wv][l31][r] = f2bf((acc[rr] + pwb[r]) * sc);
        }
        __threadfence_block();   // order wave-local LDS write->read (lockstep lanes)
        unsigned short* orow = outp + ((size_t)b * NN + n) * RR + h * 16;
        short8 lo = *(const short8*)&Lt[wv][l31][h * 16];
        *(short8*)orow = lo;                                   // [b][n][r], 32B/lane
        short8 hi = *(const short8*)&Lt[wv][l31][h * 16 + 8];
        *(short8*)(orow + 8) = hi;
    }
}

// ---------------- K3: fused attention, dbuf LDS V, quad-permuted frags ------
// grid (32, NCHUNK, B), block 256 = 4 waves. V quads stored permuted
// {0,2,1,3,4,6,5,7} so each PV B-frag is one contiguous ds_read_b128.
// O partials stored bf16.
__global__ __launch_bounds__(256, 4) void k_attn(
    const unsigned short* __restrict__ Qt, const unsigned short* __restrict__ Kt,
    const unsigned short* __restrict__ V, unsigned short* __restrict__ OPh,
    float* __restrict__ LP)
{
    __shared__ unsigned short Vt[2][32][36];   // double buffer
    int t = threadIdx.x;
    int wave = t >> 6, lane = t & 63, l31 = lane & 31, h = lane >> 5;
    int itile = blockIdx.x * 4 + wave;
    int chunk = blockIdx.y;
    int b = blockIdx.z;
    int i = itile * 32 + l31;

    const short8* qrow = (const short8*)(Qt + ((size_t)b * NN + i) * RR);
    short8 q1 = qrow[h], q2 = qrow[2 + h];

    const unsigned short* Kb = Kt + (size_t)b * NN * RR;
    const unsigned short* Vb = V + (size_t)b * RR * NN;

    int sr = t >> 3, sc = t & 7;
    int scp = (sc & 4) | ((sc & 1) << 1) | ((sc & 2) >> 1);  // {0,2,1,3,4,6,5,7}
    const unsigned short* vsrc = Vb + (size_t)sr * NN + chunk * CSIZE + sc * 4;

    floatx16 acc = {};
    float lacc = 0.f;

    // prologue: stage step-0 V tile (permuted), prefetch step-1 V and step-0 K
    *(short4v*)(&Vt[0][sr][scp * 4]) = *(const short4v*)vsrc;
    short4v vnext = *(const short4v*)(vsrc + 32);
    const short8* krow0 = (const short8*)(Kb + (size_t)(chunk * CSIZE + l31) * RR);
    short8 ka1 = krow0[h], ka2 = krow0[2 + h];
    __syncthreads();

    for (int js = 0; js < JSTEPS; js++) {
        int cur = js & 1;
        if (js + 1 < JSTEPS) *(short4v*)(&Vt[1 - cur][sr][scp * 4]) = vnext;
        if (js + 2 < JSTEPS) vnext = *(const short4v*)(vsrc + (js + 2) * 32);

        floatx16 st = {};
        st = __builtin_amdgcn_mfma_f32_32x32x16_bf16(ka1, q1, st, 0, 0, 0);
        st = __builtin_amdgcn_mfma_f32_32x32x16_bf16(ka2, q2, st, 0, 0, 0);
        int jn = (js + 1 < JSTEPS) ? js + 1 : js;
        const short8* krow = (const short8*)(Kb + (size_t)(chunk * CSIZE + jn * 32 + l31) * RR);
        ka1 = krow[h]; ka2 = krow[2 + h];

        float p[16];
        #pragma unroll
        for (int r = 0; r < 16; r++) { p[r] = exp2_fast(st[r]); lacc += p[r]; }
        union { short8 s; unsigned int u[4]; } pa1, pa2;
        #pragma unroll
        for (int r = 0; r < 8; r += 2) {
            pa1.u[r >> 1] = pk_bf16(p[r], p[r + 1]);
            pa2.u[r >> 1] = pk_bf16(p[r + 8], p[r + 9]);
        }
        // permuted rows: each B-frag = one contiguous b128 read
        const unsigned short* vrow = &Vt[cur][l31][0];
        short8 vb1 = *(const short8*)(vrow + 8 * h);
        short8 vb2 = *(const short8*)(vrow + 16 + 8 * h);
        acc = __builtin_amdgcn_mfma_f32_32x32x16_bf16(pa1.s, vb1, acc, 0, 0, 0);
        acc = __builtin_amdgcn_mfma_f32_32x32x16_bf16(pa2.s, vb2, acc, 0, 0, 0);
        __syncthreads();   // reads of Vt[cur] done; Vt[1-cur] visible for js+1
    }
    size_t slot = ((size_t)(b * 128 + itile) * NCHUNK + chunk) * 64 + lane;
    unsigned short* op = OPh + slot * 16;
    union { short8 s; unsigned int u[4]; } o1, o2;
    #pragma unroll
    for (int r = 0; r < 8; r += 2) {
        o1.u[r >> 1] = pk_bf16(acc[r], acc[r + 1]);
        o2.u[r >> 1] = pk_bf16(acc[r + 8], acc[r + 9]);
    }
    *(short8*)op = o1.s;
    *(short8*)(op + 8) = o2.s;
    LP[slot] = lacc;
}

// ---------------- K4: fused merge + 1x1 conv R->C + residual ----------------
// grid (128 itiles, B), block 256. Reduce bf16 OP chunks in-register -> Ft
// tile in LDS -> 8x mfma vs LDS-staged cw -> out = x + conv + bias.
__global__ __launch_bounds__(256, 4) void k_out(
    const float* __restrict__ x, const unsigned short* __restrict__ OPh,
    const float* __restrict__ LP, const float* __restrict__ cw,
    const float* __restrict__ cb, float* __restrict__ out)
{
    __shared__ float linv[32];
    __shared__ unsigned short Ft[32][36];     // [n_local][r]
    __shared__ unsigned short CW[256 * 36];   // cw bf16, row stride 36
    int t = threadIdx.x, lane = t & 63, l31 = lane & 31, h = lane >> 5, wv = t >> 6;
    int itile = blockIdx.x, b = blockIdx.y;
    size_t base = (size_t)(b * 128 + itile) * NCHUNK;

    // stage cw -> bf16 LDS: thread t owns row co=t (32 floats)
    {
        const float4* src = (const float4*)(cw + (size_t)t * RR);
        #pragma unroll
        for (int g = 0; g < 8; g++) {
            float4 f = src[g];
            union { short4v s; unsigned int u[2]; } s4;
            s4.u[0] = pk_bf16(f.x, f.y);
            s4.u[1] = pk_bf16(f.z, f.w);
            *(short4v*)&CW[t * 36 + g * 4] = s4.s;
        }
    }
    // reduce OP chunks: thread (lane, g=wv) owns regs 4g..4g+3 (bf16 b64 reads)
    int g = wv;
    float s0 = 0.f, s1 = 0.f, s2 = 0.f, s3 = 0.f;
    #pragma unroll
    for (int ch = 0; ch < NCHUNK; ch++) {
        short4v v = *(const short4v*)(OPh + ((base + ch) * 64 + lane) * 16 + 4 * g);
        s0 += bf2f((unsigned short)v[0]); s1 += bf2f((unsigned short)v[1]);
        s2 += bf2f((unsigned short)v[2]); s3 += bf2f((unsigned short)v[3]);
    }
    // softmax denominators (rows i_local = t<32)
    if (t < 32) {
        float sl = 0.f;
        #pragma unroll
        for (int ch = 0; ch < NCHUNK; ch++) {
            sl += LP[(base + ch) * 64 + t] + LP[(base + ch) * 64 + t + 32];
        }
        linv[t] = 1.f / sl;
    }
    __syncthreads();   // linv + CW ready
    {
        float sv[4] = {s0, s1, s2, s3};
        #pragma unroll
        for (int j = 0; j < 4; j++) {
            int reg = 4 * g + j;
            int il = (reg & 3) + 8 * (reg >> 2) + 4 * h;   // C/D row mapping
            Ft[il][l31] = f2bf(sv[j] * linv[il]);          // r = l31 channel
        }
    }
    __syncthreads();   // Ft ready
    // convout: wave wv does co-tiles 2wv, 2wv+1
    #pragma unroll
    for (int cti = 0; cti < 2; cti++) {
        int co0 = (wv * 2 + cti) * 32;
        const unsigned short* arow = &CW[(co0 + l31) * 36 + 8 * h];
        union { short8 s; short4v hh[2]; } a1, a2, b1, b2;
        a1.hh[0] = *(const short4v*)arow;
        a1.hh[1] = *(const short4v*)(arow + 4);
        a2.hh[0] = *(const short4v*)(arow + 16);
        a2.hh[1] = *(const short4v*)(arow + 20);
        const unsigned short* brow = &Ft[l31][8 * h];
        b1.hh[0] = *(const short4v*)brow;
        b1.hh[1] = *(const short4v*)(brow + 4);
        b2.hh[0] = *(const short4v*)(brow + 16);
        b2.hh[1] = *(const short4v*)(brow + 20);
        floatx16 acc = {};
        acc = __builtin_amdgcn_mfma_f32_32x32x16_bf16(a1.s, b1.s, acc, 0, 0, 0);
        acc = __builtin_amdgcn_mfma_f32_32x32x16_bf16(a2.s, b2.s, acc, 0, 0, 0);
        #pragma unroll
        for (int rr = 0; rr < 16; rr++) {
            int co = co0 + (rr & 3) + 8 * (rr >> 2) + 4 * h;
            size_t o = ((size_t)(b * CC + co)) * NN + itile * 32 + l31;
            out[o] = x[o] + acc[rr] + cb[co];
        }
    }
}

extern "C" void kernel_launch(void* const* d_in, const int* in_sizes, int n_in,
                              void* d_out, int out_size, void* d_ws, size_t ws_size,
                              hipStream_t stream) {
    const float* x = (const float*)d_in[0];
    char* ws = (char*)d_ws;
    // D (24 MB, dead after k_pw) aliases OPh (8 MB bf16, written by k_attn)
    unsigned short* Dq  = (unsigned short*)(ws);              // 24 MB [p][b][c][n]
    unsigned short* OPh = (unsigned short*)(ws);              // 8 MB (alias of D)
    unsigned short* Qt  = (unsigned short*)(ws + 25165824);   // 1 MB (b,n,r)
    unsigned short* Kt  = (unsigned short*)(ws + 26214400);   // 1 MB (b,n,r)
    unsigned short* V   = (unsigned short*)(ws + 27262976);   // 1 MB (b,r,n)
    float*          LP  = (float*)(ws + 28311552);            // 1 MB

    hipLaunchKernelGGL(k_dw, dim3(CC, BB), dim3(256), 0, stream, x,
                       (const float*)d_in[1], (const float*)d_in[2],
                       (const float*)d_in[5], (const float*)d_in[6],
                       (const float*)d_in[9], (const float*)d_in[10], Dq);
    hipLaunchKernelGGL(k_pw, dim3(32, 3, BB), dim3(256), 0, stream, Dq,
                       (const float*)d_in[3], (const float*)d_in[4],
                       (const float*)d_in[7], (const float*)d_in[8],
                       (const float*)d_in[11], (const float*)d_in[12],
                       V, Qt, Kt);
    hipLaunchKernelGGL(k_attn, dim3(32, NCHUNK, BB), dim3(256), 0, stream,
                       Qt, Kt, V, OPh, LP);
    hipLaunchKernelGGL(k_out, dim3(128, BB), dim3(256), 0, stream,
                       x, OPh, LP, (const float*)d_in[13], (const float*)d_in[14],
                       (float*)d_out);
}